// Round 5
// baseline (311.538 us; speedup 1.0000x reference)
//
#include <hip/hip_runtime.h>
#include <math.h>

// DeformableAttention2D — round 3 kernel (2nd resubmit; infra failures in
// rounds 3 and 4, never measured):
// transposed weights + coalesced matvecs, 4-rows-per-block k2,
// transposed K/V layout for k3b.
// Sizes (fixed): B=4, N=256, DIM=256, HEADS=8, GROUPS=8, INNER=512, DH=64,
// cross-attn head dim 32, rgb 4x4 (16 tokens), CPB MLP 2->64->64->1.

#define DIMC 256
#define NQ 256
#define HEADS 8
#define GROUPS 8
#define INNER 512
#define DH 64
#define HDX 32
#define HWT 16

typedef __attribute__((ext_vector_type(8))) short short8v;
typedef __attribute__((ext_vector_type(4))) float f32x4;
typedef unsigned short ushort_t;

__device__ __forceinline__ float gelu_exact(float x) {
    return 0.5f * x * (1.f + erff(x * 0.70710678118654752f));
}
__device__ __forceinline__ short f2bf(float x) {
    union { float f; unsigned u; } c; c.f = x;
    unsigned r = c.u + 0x7fffu + ((c.u >> 16) & 1u);
    return (short)(r >> 16);
}
__device__ __forceinline__ float bf2f(ushort_t h) {
    union { unsigned u; float f; } c; c.u = ((unsigned)h) << 16;
    return c.f;
}
__device__ __forceinline__ float samp4(const float* __restrict__ img, int yi, int xi) {
    bool valid = (xi >= 0) && (xi < 4) && (yi >= 0) && (yi < 4);
    int idx = min(max(yi, 0), 3) * 4 + min(max(xi, 0), 3);
    return valid ? img[idx] : 0.f;
}

// ---------------- K0: weight transposes ----------------
// WqT[d][o]=in_w[o][d]; mowT[d][o]=mow[o][d]; owT[c][o]=out_w[o][c];
// qwT/kwT/vwT[ci][ch]=w[ch][ci]
__global__ __launch_bounds__(256) void k0_tr(
        const float* __restrict__ in_w, const float* __restrict__ mow,
        const float* __restrict__ out_w, const float* __restrict__ q_w,
        const float* __restrict__ k_w, const float* __restrict__ v_w,
        float* __restrict__ WqT, float* __restrict__ mowT,
        float* __restrict__ owT, float* __restrict__ qwT,
        float* __restrict__ kwT, float* __restrict__ vwT) {
    int idx = blockIdx.x * 256 + threadIdx.x;
    if (idx < 65536) {
        int d = idx >> 8, o = idx & 255;
        WqT[idx] = in_w[o * 256 + d];
    } else if (idx < 131072) {
        int k = idx - 65536; int d = k >> 8, o = k & 255;
        mowT[k] = mow[o * 256 + d];
    } else if (idx < 262144) {
        int k = idx - 131072; int c = k >> 8, o = k & 255;
        owT[k] = out_w[o * 512 + c];
    } else if (idx < 278528) {
        int k = idx - 262144; int ci = k >> 9, ch = k & 511;
        qwT[k] = q_w[ch * 32 + ci];
    } else if (idx < 294912) {
        int k = idx - 278528; int ci = k >> 9, ch = k & 511;
        kwT[k] = k_w[ch * 32 + ci];
    } else if (idx < 311296) {
        int k = idx - 294912; int ci = k >> 9, ch = k & 511;
        vwT[k] = v_w[ch * 32 + ci];
    }
}

// ---------------- K1: kx, vx  [b,16,256] ----------------
__global__ __launch_bounds__(256) void k1_kv(const float* __restrict__ rgb,
        const float* __restrict__ in_w, const float* __restrict__ in_b,
        float* __restrict__ kx, float* __restrict__ vx) {
    int b = blockIdx.x >> 4;
    int tt = blockIdx.x & 15;
    int c = threadIdx.x;
    __shared__ __align__(16) float kvin[DIMC];
    float ang = (float)tt * powf(10000.f, -(float)(c >> 1) * (1.f / 128.f));
    float sv = (c & 1) ? cosf(ang) : sinf(ang);
    kvin[c] = rgb[(b * DIMC + c) * HWT + tt] + sv;
    __syncthreads();
    const float4* x4 = (const float4*)kvin;
    const float4* wk4 = (const float4*)(in_w + (DIMC + c) * DIMC);
    const float4* wv4 = (const float4*)(in_w + (2 * DIMC + c) * DIMC);
    float ak0 = in_b[DIMC + c], ak1 = 0.f, av0 = in_b[2 * DIMC + c], av1 = 0.f;
    #pragma unroll 4
    for (int d4 = 0; d4 < 64; ++d4) {
        float4 x = x4[d4], wk = wk4[d4], wv = wv4[d4];
        ak0 = fmaf(wk.x, x.x, ak0); ak1 = fmaf(wk.y, x.y, ak1);
        ak0 = fmaf(wk.z, x.z, ak0); ak1 = fmaf(wk.w, x.w, ak1);
        av0 = fmaf(wv.x, x.x, av0); av1 = fmaf(wv.y, x.y, av1);
        av0 = fmaf(wv.z, x.z, av0); av1 = fmaf(wv.w, x.w, av1);
    }
    kx[(b * HWT + tt) * DIMC + c] = ak0 + ak1;
    vx[(b * HWT + tt) * DIMC + c] = av0 + av1;
}

// ---------------- K2: 4 rows per block ----------------
__global__ __launch_bounds__(256) void k2_qkv(
        const float* __restrict__ pose_feat, const float* __restrict__ rgb,
        const float* __restrict__ pose_init, const float* __restrict__ in_b,
        const float* __restrict__ WqT, const float* __restrict__ mowT,
        const float* __restrict__ mob, const float* __restrict__ pe_gauss,
        const float* __restrict__ off_w1, const float* __restrict__ off_b1,
        const float* __restrict__ off_w2,
        const float* __restrict__ qwT, const float* __restrict__ kwT,
        const float* __restrict__ vwT,
        const float* __restrict__ kx, const float* __restrict__ vx,
        float* __restrict__ qT, float* __restrict__ kTt, float* __restrict__ vTt,
        float* __restrict__ vgrid_g) {
    int b = blockIdx.x >> 6;
    int n0 = (blockIdx.x & 63) * 4;
    int t = threadIdx.x;
    __shared__ __align__(16) float xs[4][DIMC];
    __shared__ __align__(16) float qxs[4][DIMC];
    __shared__ __align__(16) float ctx[4][DIMC];
    __shared__ __align__(16) float x2[4][DIMC];
    __shared__ float lg[4][128], psm[4][128];
    __shared__ float qls[4][INNER];
    __shared__ float kvs[4][DIMC];
    __shared__ float vg[4][GROUPS][2];
    __shared__ float g01[4][2];

    if (t < 8) {
        int r = t >> 1, comp = t & 1;
        g01[r][comp] = 2.f * pose_init[(b * 2 + comp) * NQ + n0 + r] - 1.f;
    }
    float4 pf4 = *(const float4*)(pose_feat + (b * DIMC + t) * NQ + n0);
    float pfv[4] = {pf4.x, pf4.y, pf4.z, pf4.w};
    __syncthreads();
    // xs[r][t] = pose_feat + point_emb
    {
        int j = t & 127;
        float pj0 = pe_gauss[j], pj1 = pe_gauss[128 + j];
        #pragma unroll
        for (int r = 0; r < 4; ++r) {
            float cc = (g01[r][0] * pj0 + g01[r][1] * pj1) * 6.28318530717958648f;
            float sc = (t < 128) ? sinf(cc) : cosf(cc);
            xs[r][t] = pfv[r] + sc;
        }
    }
    __syncthreads();
    // qx matvec (coalesced WqT)
    {
        float bq = in_b[t];
        float a0 = bq, a1 = bq, a2 = bq, a3 = bq;
        #pragma unroll 2
        for (int d4 = 0; d4 < 64; ++d4) {
            int d = d4 * 4;
            float w0 = WqT[(d + 0) * DIMC + t];
            float w1 = WqT[(d + 1) * DIMC + t];
            float w2 = WqT[(d + 2) * DIMC + t];
            float w3 = WqT[(d + 3) * DIMC + t];
            float4 x0 = *(const float4*)&xs[0][d];
            float4 x1 = *(const float4*)&xs[1][d];
            float4 x2_ = *(const float4*)&xs[2][d];
            float4 x3 = *(const float4*)&xs[3][d];
            a0 = fmaf(w0, x0.x, a0); a0 = fmaf(w1, x0.y, a0); a0 = fmaf(w2, x0.z, a0); a0 = fmaf(w3, x0.w, a0);
            a1 = fmaf(w0, x1.x, a1); a1 = fmaf(w1, x1.y, a1); a1 = fmaf(w2, x1.z, a1); a1 = fmaf(w3, x1.w, a1);
            a2 = fmaf(w0, x2_.x, a2); a2 = fmaf(w1, x2_.y, a2); a2 = fmaf(w2, x2_.z, a2); a2 = fmaf(w3, x2_.w, a2);
            a3 = fmaf(w0, x3.x, a3); a3 = fmaf(w1, x3.y, a3); a3 = fmaf(w2, x3.z, a3); a3 = fmaf(w3, x3.w, a3);
        }
        qxs[0][t] = a0; qxs[1][t] = a1; qxs[2][t] = a2; qxs[3][t] = a3;
    }
    __syncthreads();
    // cross-attn logits: 4r x 8h x 16tt
    #pragma unroll
    for (int rep = 0; rep < 2; ++rep) {
        int idx = rep * 256 + t;
        int r = idx >> 7, hh = (idx >> 4) & 7, tt = idx & 15;
        const float4* kp = (const float4*)(kx + (b * HWT + tt) * DIMC + hh * HDX);
        const float4* qp = (const float4*)(&qxs[r][hh * HDX]);
        float a = 0.f;
        #pragma unroll
        for (int d4 = 0; d4 < 8; ++d4) {
            float4 k4 = kp[d4], q4 = qp[d4];
            a = fmaf(q4.x, k4.x, a); a = fmaf(q4.y, k4.y, a);
            a = fmaf(q4.z, k4.z, a); a = fmaf(q4.w, k4.w, a);
        }
        lg[r][hh * 16 + tt] = a * 0.17677669529663689f;
    }
    __syncthreads();
    if (t < 32) {
        int r = t >> 3, hh = t & 7;
        float m = -1e30f;
        for (int tt = 0; tt < 16; ++tt) m = fmaxf(m, lg[r][hh * 16 + tt]);
        float s = 0.f;
        for (int tt = 0; tt < 16; ++tt) {
            float e = __expf(lg[r][hh * 16 + tt] - m);
            psm[r][hh * 16 + tt] = e; s += e;
        }
        float rr = 1.f / s;
        for (int tt = 0; tt < 16; ++tt) psm[r][hh * 16 + tt] *= rr;
    }
    __syncthreads();
    // ctx[r][t]
    {
        int hh = t >> 5;
        const float* vp = vx + b * HWT * DIMC + t;
        float a0 = 0.f, a1 = 0.f, a2 = 0.f, a3 = 0.f;
        #pragma unroll
        for (int tt = 0; tt < 16; ++tt) {
            float vv = vp[tt * DIMC];
            a0 = fmaf(psm[0][hh * 16 + tt], vv, a0);
            a1 = fmaf(psm[1][hh * 16 + tt], vv, a1);
            a2 = fmaf(psm[2][hh * 16 + tt], vv, a2);
            a3 = fmaf(psm[3][hh * 16 + tt], vv, a3);
        }
        ctx[0][t] = a0; ctx[1][t] = a1; ctx[2][t] = a2; ctx[3][t] = a3;
    }
    __syncthreads();
    // pose_cross matvec + residual
    {
        float bm = mob[t];
        float a0 = bm, a1 = bm, a2 = bm, a3 = bm;
        #pragma unroll 2
        for (int d4 = 0; d4 < 64; ++d4) {
            int d = d4 * 4;
            float w0 = mowT[(d + 0) * DIMC + t];
            float w1 = mowT[(d + 1) * DIMC + t];
            float w2 = mowT[(d + 2) * DIMC + t];
            float w3 = mowT[(d + 3) * DIMC + t];
            float4 c0 = *(const float4*)&ctx[0][d];
            float4 c1 = *(const float4*)&ctx[1][d];
            float4 c2 = *(const float4*)&ctx[2][d];
            float4 c3 = *(const float4*)&ctx[3][d];
            a0 = fmaf(w0, c0.x, a0); a0 = fmaf(w1, c0.y, a0); a0 = fmaf(w2, c0.z, a0); a0 = fmaf(w3, c0.w, a0);
            a1 = fmaf(w0, c1.x, a1); a1 = fmaf(w1, c1.y, a1); a1 = fmaf(w2, c1.z, a1); a1 = fmaf(w3, c1.w, a1);
            a2 = fmaf(w0, c2.x, a2); a2 = fmaf(w1, c2.y, a2); a2 = fmaf(w2, c2.z, a2); a2 = fmaf(w3, c2.w, a2);
            a3 = fmaf(w0, c3.x, a3); a3 = fmaf(w1, c3.y, a3); a3 = fmaf(w2, c3.z, a3); a3 = fmaf(w3, c3.w, a3);
        }
        x2[0][t] = pfv[0] + a0; x2[1][t] = pfv[1] + a1;
        x2[2][t] = pfv[2] + a2; x2[3][t] = pfv[3] + a3;
    }
    __syncthreads();
    // grouped q conv: thread=ch (2 reps), 4 rows
    #pragma unroll
    for (int rep = 0; rep < 2; ++rep) {
        int ch = rep * 256 + t;
        int g = ch >> 6;
        float aq[4] = {0.f, 0.f, 0.f, 0.f};
        #pragma unroll
        for (int ci = 0; ci < 32; ++ci) {
            float w = qwT[ci * INNER + ch];
            aq[0] = fmaf(w, x2[0][g * 32 + ci], aq[0]);
            aq[1] = fmaf(w, x2[1][g * 32 + ci], aq[1]);
            aq[2] = fmaf(w, x2[2][g * 32 + ci], aq[2]);
            aq[3] = fmaf(w, x2[3][g * 32 + ci], aq[3]);
        }
        #pragma unroll
        for (int r = 0; r < 4; ++r) {
            qls[r][ch] = aq[r];
            qT[(b * NQ + n0 + r) * INNER + ch] = aq[r];
        }
    }
    __syncthreads();
    // offsets: 32 (r,g) pairs x 8 lanes
    {
        int pr = t >> 3, l = t & 7;
        int r = pr >> 3, g = pr & 7;
        float s0 = 0.f, s1 = 0.f;
        #pragma unroll
        for (int e = 0; e < 8; ++e) {
            int jj = l * 8 + e;
            float ev = gelu_exact(fmaf(qls[r][g * 64 + jj], off_w1[jj], off_b1[jj]));
            s0 = fmaf(ev, off_w2[jj], s0);
            s1 = fmaf(ev, off_w2[64 + jj], s1);
        }
        #pragma unroll
        for (int o = 4; o > 0; o >>= 1) {
            s0 += __shfl_xor(s0, o, 64);
            s1 += __shfl_xor(s1, o, 64);
        }
        if (l == 0) {
            float vgx = g01[r][0] + tanhf(s0) * (2.f / 3.f);
            float vgy = g01[r][1] + tanhf(s1) * (2.f / 3.f);
            vg[r][g][0] = vgx; vg[r][g][1] = vgy;
            float* vp = vgrid_g + ((b * GROUPS + g) * NQ + n0 + r) * 2;
            vp[0] = vgx; vp[1] = vgy;
        }
    }
    __syncthreads();
    // bilinear grid sample: 4r x 256c
    #pragma unroll
    for (int rep = 0; rep < 4; ++rep) {
        int idx = rep * 256 + t;
        int r = idx >> 8, c = idx & 255, g = c >> 5;
        float x = (vg[r][g][0] + 1.f) * 2.f - 0.5f;
        float y = (vg[r][g][1] + 1.f) * 2.f - 0.5f;
        float x0f = floorf(x), y0f = floorf(y);
        float wx = x - x0f, wy = y - y0f;
        int x0 = (int)x0f, y0 = (int)y0f;
        const float* img = rgb + (b * DIMC + c) * HWT;
        float v00 = samp4(img, y0, x0), v01 = samp4(img, y0, x0 + 1);
        float v10 = samp4(img, y0 + 1, x0), v11 = samp4(img, y0 + 1, x0 + 1);
        kvs[r][c] = v00 * (1.f - wx) * (1.f - wy) + v01 * wx * (1.f - wy)
                  + v10 * (1.f - wx) * wy + v11 * wx * wy;
    }
    __syncthreads();
    // grouped k/v convs: thread=ch (2 reps), 4 rows; write transposed [bg][d][n]
    #pragma unroll
    for (int rep = 0; rep < 2; ++rep) {
        int ch = rep * 256 + t;
        int g = ch >> 6;
        float ak[4] = {0.f, 0.f, 0.f, 0.f};
        float av[4] = {0.f, 0.f, 0.f, 0.f};
        #pragma unroll
        for (int ci = 0; ci < 32; ++ci) {
            float wk = kwT[ci * INNER + ch];
            float wv = vwT[ci * INNER + ch];
            #pragma unroll
            for (int r = 0; r < 4; ++r) {
                float x = kvs[r][g * 32 + ci];
                ak[r] = fmaf(wk, x, ak[r]);
                av[r] = fmaf(wv, x, av[r]);
            }
        }
        int hh = ch >> 6, dh = ch & 63;
        float4 kk; kk.x = ak[0]; kk.y = ak[1]; kk.z = ak[2]; kk.w = ak[3];
        float4 vv; vv.x = av[0]; vv.y = av[1]; vv.z = av[2]; vv.w = av[3];
        *(float4*)(kTt + ((b * HEADS + hh) * DH + dh) * NQ + n0) = kk;
        *(float4*)(vTt + ((b * HEADS + hh) * DH + dh) * NQ + n0) = vv;
    }
}

// ---------------- K3a: CPB bias via MFMA ----------------
__global__ __launch_bounds__(256) void k3a_bias(
        const float* __restrict__ pose_init, const float* __restrict__ vgrid_g,
        const float* __restrict__ w0, const float* __restrict__ b0,
        const float* __restrict__ w1, const float* __restrict__ b1,
        const float* __restrict__ w2, const float* __restrict__ b2,
        ushort_t* __restrict__ bias) {
    int bg = blockIdx.x >> 4;
    int jt = blockIdx.x & 15;
    int b = bg >> 3;
    int tid = threadIdx.x;
    int wv = tid >> 6, lane = tid & 63;
    int lgp = lane >> 4, lr = lane & 15;

    __shared__ float gx_s[NQ], gy_s[NQ];
    gx_s[tid] = 2.f * pose_init[(b * 2 + 0) * NQ + tid] - 1.f;
    gy_s[tid] = 2.f * pose_init[(b * 2 + 1) * NQ + tid] - 1.f;
    __syncthreads();

    float w0a[2][8], w0b[2][8], b0r[2][8];
    short8v bw1[2][4];
    float b1r[4], w2r[4];
    #pragma unroll
    for (int kc = 0; kc < 2; ++kc)
        #pragma unroll
        for (int e = 0; e < 8; ++e) {
            int c = kc * 32 + lgp * 8 + e;
            w0a[kc][e] = w0[2 * c];
            w0b[kc][e] = w0[2 * c + 1];
            b0r[kc][e] = b0[c];
        }
    #pragma unroll
    for (int nt = 0; nt < 4; ++nt) {
        int c2 = nt * 16 + lr;
        b1r[nt] = b1[c2];
        w2r[nt] = w2[c2];
        #pragma unroll
        for (int kc = 0; kc < 2; ++kc)
            #pragma unroll
            for (int e = 0; e < 8; ++e)
                bw1[kc][nt][e] = f2bf(w1[c2 * 64 + kc * 32 + lgp * 8 + e]);
    }
    float b2v = b2[0];

    int j0 = jt * 16 + wv * 4;
    const float* vgp = vgrid_g + bg * NQ * 2;
    #pragma unroll 1
    for (int it = 0; it < 16; ++it) {
        int i = it * 16 + lr;
        float gxi = gx_s[i], gyi = gy_s[i];
        #pragma unroll 1
        for (int jj = 0; jj < 4; ++jj) {
            int j = j0 + jj;
            float vgx = vgp[j * 2], vgy = vgp[j * 2 + 1];
            float px = gxi - vgx, py = gyi - vgy;
            float u = copysignf(__logf(1.f + fabsf(px)), px);
            float vvl = copysignf(__logf(1.f + fabsf(py)), py);
            short8v a0, a1;
            #pragma unroll
            for (int e = 0; e < 8; ++e) {
                float h = fmaf(w0a[0][e], u, fmaf(w0b[0][e], vvl, b0r[0][e]));
                a0[e] = f2bf(fmaxf(h, 0.f));
            }
            #pragma unroll
            for (int e = 0; e < 8; ++e) {
                float h = fmaf(w0a[1][e], u, fmaf(w0b[1][e], vvl, b0r[1][e]));
                a1[e] = f2bf(fmaxf(h, 0.f));
            }
            f32x4 acc0 = {0.f, 0.f, 0.f, 0.f};
            f32x4 acc1 = {0.f, 0.f, 0.f, 0.f};
            f32x4 acc2 = {0.f, 0.f, 0.f, 0.f};
            f32x4 acc3 = {0.f, 0.f, 0.f, 0.f};
            acc0 = __builtin_amdgcn_mfma_f32_16x16x32_bf16(a0, bw1[0][0], acc0, 0, 0, 0);
            acc0 = __builtin_amdgcn_mfma_f32_16x16x32_bf16(a1, bw1[1][0], acc0, 0, 0, 0);
            acc1 = __builtin_amdgcn_mfma_f32_16x16x32_bf16(a0, bw1[0][1], acc1, 0, 0, 0);
            acc1 = __builtin_amdgcn_mfma_f32_16x16x32_bf16(a1, bw1[1][1], acc1, 0, 0, 0);
            acc2 = __builtin_amdgcn_mfma_f32_16x16x32_bf16(a0, bw1[0][2], acc2, 0, 0, 0);
            acc2 = __builtin_amdgcn_mfma_f32_16x16x32_bf16(a1, bw1[1][2], acc2, 0, 0, 0);
            acc3 = __builtin_amdgcn_mfma_f32_16x16x32_bf16(a0, bw1[0][3], acc3, 0, 0, 0);
            acc3 = __builtin_amdgcn_mfma_f32_16x16x32_bf16(a1, bw1[1][3], acc3, 0, 0, 0);
            #pragma unroll
            for (int r = 0; r < 4; ++r) {
                float s = fmaxf(acc0[r] + b1r[0], 0.f) * w2r[0]
                        + fmaxf(acc1[r] + b1r[1], 0.f) * w2r[1]
                        + fmaxf(acc2[r] + b1r[2], 0.f) * w2r[2]
                        + fmaxf(acc3[r] + b1r[3], 0.f) * w2r[3];
                s += __shfl_xor(s, 1, 64);
                s += __shfl_xor(s, 2, 64);
                s += __shfl_xor(s, 4, 64);
                s += __shfl_xor(s, 8, 64);
                if (lr == 0)
                    bias[(bg * NQ + it * 16 + lgp * 4 + r) * NQ + j] = (ushort_t)f2bf(s + b2v);
            }
        }
    }
}

// ---------------- K3b: sim + bias + softmax + attn@V (transposed K/V) ----------------
__global__ __launch_bounds__(256) void k3b_attn(
        const float* __restrict__ qT, const float* __restrict__ kTt,
        const float* __restrict__ vTt, const ushort_t* __restrict__ bias,
        float* __restrict__ aoT) {
    int bg = blockIdx.x >> 5;
    int itile = blockIdx.x & 31;
    int b = bg >> 3, h = bg & 7;
    int i0 = itile * 8;
    int tid = threadIdx.x;
    int il = tid >> 5, lane = tid & 31;

    __shared__ __align__(16) float q_s[8][64];
    __shared__ __align__(16) float attn_s[8][NQ];
    __shared__ float ssum_s[8];

    for (int idx = tid; idx < 8 * 64; idx += 256) {
        int i = idx >> 6, d = idx & 63;
        q_s[i][d] = qT[(b * NQ + i0 + i) * INNER + h * 64 + d] * 0.125f;
    }
    __syncthreads();

    const float* kb = kTt + bg * DH * NQ;
    const ushort_t* brow = bias + (bg * NQ + i0 + il) * NQ;
    #pragma unroll 1
    for (int jj = 0; jj < 8; ++jj) {
        int j = jj * 32 + lane;
        float a0 = 0.f, a1 = 0.f, a2 = 0.f, a3 = 0.f;
        #pragma unroll
        for (int d4 = 0; d4 < 16; ++d4) {
            int d = d4 * 4;
            a0 = fmaf(q_s[il][d + 0], kb[(d + 0) * NQ + j], a0);
            a1 = fmaf(q_s[il][d + 1], kb[(d + 1) * NQ + j], a1);
            a2 = fmaf(q_s[il][d + 2], kb[(d + 2) * NQ + j], a2);
            a3 = fmaf(q_s[il][d + 3], kb[(d + 3) * NQ + j], a3);
        }
        attn_s[il][j] = (a0 + a1) + (a2 + a3) + bf2f(brow[j]);
    }
    __syncthreads();
    {
        float m = -1e30f;
        for (int jj = 0; jj < 8; ++jj) m = fmaxf(m, attn_s[il][jj * 32 + lane]);
        #pragma unroll
        for (int o = 16; o > 0; o >>= 1) m = fmaxf(m, __shfl_xor(m, o, 32));
        float s = 0.f;
        for (int jj = 0; jj < 8; ++jj) {
            int j = jj * 32 + lane;
            float e = __expf(attn_s[il][j] - m);
            attn_s[il][j] = e;
            s += e;
        }
        #pragma unroll
        for (int o = 16; o > 0; o >>= 1) s += __shfl_xor(s, o, 32);
        if (lane == 0) ssum_s[il] = s;
    }
    __syncthreads();
    // PV: thread = (i2 = tid>>6 in 0..3 covering i2, i2+4; d = tid&63)
    {
        int d = tid & 63, i2 = tid >> 6;
        const float4* vr4 = (const float4*)(vTt + (bg * DH + d) * NQ);
        float acc0 = 0.f, acc1 = 0.f;
        #pragma unroll 4
        for (int j4 = 0; j4 < 64; ++j4) {
            float4 vv = vr4[j4];
            float4 al = *(const float4*)&attn_s[i2][j4 * 4];
            float4 ah = *(const float4*)&attn_s[i2 + 4][j4 * 4];
            acc0 = fmaf(al.x, vv.x, acc0); acc0 = fmaf(al.y, vv.y, acc0);
            acc0 = fmaf(al.z, vv.z, acc0); acc0 = fmaf(al.w, vv.w, acc0);
            acc1 = fmaf(ah.x, vv.x, acc1); acc1 = fmaf(ah.y, vv.y, acc1);
            acc1 = fmaf(ah.z, vv.z, acc1); acc1 = fmaf(ah.w, vv.w, acc1);
        }
        float r0 = 1.f / ssum_s[i2], r1 = 1.f / ssum_s[i2 + 4];
        aoT[(b * NQ + i0 + i2) * INNER + h * 64 + d] = acc0 * r0;
        aoT[(b * NQ + i0 + i2 + 4) * INNER + h * 64 + d] = acc1 * r1;
    }
}

// ---------------- K4: final projection 512 -> 256 (coalesced owT) ----------------
__global__ __launch_bounds__(256) void k4_proj(const float* __restrict__ aoT,
        const float* __restrict__ owT, const float* __restrict__ out_b,
        float* __restrict__ out) {
    int b = blockIdx.x >> 6;
    int n0 = (blockIdx.x & 63) * 4;
    int t = threadIdx.x;
    __shared__ __align__(16) float xl[4][INNER];
    for (int idx = t; idx < 4 * INNER; idx += 256) {
        xl[idx >> 9][idx & 511] = aoT[(b * NQ + n0) * INNER + idx];
    }
    __syncthreads();
    float bo = out_b[t];
    float a0 = bo, a1 = bo, a2 = bo, a3 = bo;
    #pragma unroll 2
    for (int c4 = 0; c4 < 128; ++c4) {
        int c = c4 * 4;
        float w0 = owT[(c + 0) * DIMC + t];
        float w1 = owT[(c + 1) * DIMC + t];
        float w2 = owT[(c + 2) * DIMC + t];
        float w3 = owT[(c + 3) * DIMC + t];
        float4 x0 = *(const float4*)&xl[0][c];
        float4 x1 = *(const float4*)&xl[1][c];
        float4 x2 = *(const float4*)&xl[2][c];
        float4 x3 = *(const float4*)&xl[3][c];
        a0 = fmaf(w0, x0.x, a0); a0 = fmaf(w1, x0.y, a0); a0 = fmaf(w2, x0.z, a0); a0 = fmaf(w3, x0.w, a0);
        a1 = fmaf(w0, x1.x, a1); a1 = fmaf(w1, x1.y, a1); a1 = fmaf(w2, x1.z, a1); a1 = fmaf(w3, x1.w, a1);
        a2 = fmaf(w0, x2.x, a2); a2 = fmaf(w1, x2.y, a2); a2 = fmaf(w2, x2.z, a2); a2 = fmaf(w3, x2.w, a2);
        a3 = fmaf(w0, x3.x, a3); a3 = fmaf(w1, x3.y, a3); a3 = fmaf(w2, x3.z, a3); a3 = fmaf(w3, x3.w, a3);
    }
    float4 res; res.x = a0; res.y = a1; res.z = a2; res.w = a3;
    *(float4*)(out + (b * DIMC + t) * NQ + n0) = res;
}

extern "C" void kernel_launch(void* const* d_in, const int* in_sizes, int n_in,
                              void* d_out, int out_size, void* d_ws, size_t ws_size,
                              hipStream_t stream) {
    const float* pose_feat = (const float*)d_in[0];
    const float* rgb       = (const float*)d_in[1];
    const float* pose_init = (const float*)d_in[2];
    const float* mha_in_w  = (const float*)d_in[3];
    const float* mha_in_b  = (const float*)d_in[4];
    const float* mha_out_w = (const float*)d_in[5];
    const float* mha_out_b = (const float*)d_in[6];
    const float* pe_gauss  = (const float*)d_in[7];
    const float* off_w1    = (const float*)d_in[8];
    const float* off_b1    = (const float*)d_in[9];
    const float* off_w2    = (const float*)d_in[10];
    const float* cpb_w0    = (const float*)d_in[11];
    const float* cpb_b0    = (const float*)d_in[12];
    const float* cpb_w1    = (const float*)d_in[13];
    const float* cpb_b1    = (const float*)d_in[14];
    const float* cpb_w2    = (const float*)d_in[15];
    const float* cpb_b2    = (const float*)d_in[16];
    const float* q_w       = (const float*)d_in[17];
    const float* k_w       = (const float*)d_in[18];
    const float* v_w       = (const float*)d_in[19];
    const float* out_w     = (const float*)d_in[20];
    const float* out_b     = (const float*)d_in[21];

    float* ws    = (float*)d_ws;
    float* kx    = ws;                     // 16384
    float* vx    = kx + 16384;             // 16384
    float* qT    = vx + 16384;             // 524288
    float* kTt   = qT + 524288;            // 524288
    float* vTt   = kTt + 524288;           // 524288
    float* vgrid = vTt + 524288;           // 16384
    float* aoT   = vgrid + 16384;          // 524288
    float* WqT   = aoT + 524288;           // 65536
    float* mowT  = WqT + 65536;            // 65536
    float* owT   = mowT + 65536;           // 131072
    float* qwT   = owT + 131072;           // 16384
    float* kwT   = qwT + 16384;            // 16384
    float* vwT   = kwT + 16384;            // 16384
    ushort_t* bias = (ushort_t*)(vwT + 16384);   // 32*256*256 bf16 = 4 MB
    float* out   = (float*)d_out;

    k0_tr<<<1216, 256, 0, stream>>>(mha_in_w, mha_out_w, out_w, q_w, k_w, v_w,
        WqT, mowT, owT, qwT, kwT, vwT);
    k1_kv<<<64, 256, 0, stream>>>(rgb, mha_in_w, mha_in_b, kx, vx);
    k2_qkv<<<256, 256, 0, stream>>>(pose_feat, rgb, pose_init, mha_in_b,
        WqT, mowT, mha_out_b, pe_gauss, off_w1, off_b1, off_w2, qwT, kwT, vwT,
        kx, vx, qT, kTt, vTt, vgrid);
    k3a_bias<<<512, 256, 0, stream>>>(pose_init, vgrid,
        cpb_w0, cpb_b0, cpb_w1, cpb_b1, cpb_w2, cpb_b2, bias);
    k3b_attn<<<1024, 256, 0, stream>>>(qT, kTt, vTt, bias, aoT);
    k4_proj<<<256, 256, 0, stream>>>(aoT, owT, out_b, out);
}

// Round 6
// 209.097 us; speedup vs baseline: 1.4899x; 1.4899x over previous
//
#include <hip/hip_runtime.h>
#include <math.h>

// DeformableAttention2D — round 6: k3b both phases coalesced.
// sim: K in [d][j] with float4-over-j loads; PV: V back in [n][d] layout
// (round-2 coalesced pattern). Everything else unchanged from round 3.
// Sizes (fixed): B=4, N=256, DIM=256, HEADS=8, GROUPS=8, INNER=512, DH=64,
// cross-attn head dim 32, rgb 4x4 (16 tokens), CPB MLP 2->64->64->1.

#define DIMC 256
#define NQ 256
#define HEADS 8
#define GROUPS 8
#define INNER 512
#define DH 64
#define HDX 32
#define HWT 16

typedef __attribute__((ext_vector_type(8))) short short8v;
typedef __attribute__((ext_vector_type(4))) float f32x4;
typedef unsigned short ushort_t;

__device__ __forceinline__ float gelu_exact(float x) {
    return 0.5f * x * (1.f + erff(x * 0.70710678118654752f));
}
__device__ __forceinline__ short f2bf(float x) {
    union { float f; unsigned u; } c; c.f = x;
    unsigned r = c.u + 0x7fffu + ((c.u >> 16) & 1u);
    return (short)(r >> 16);
}
__device__ __forceinline__ float bf2f(unsigned hbits) {
    union { unsigned u; float f; } c; c.u = hbits << 16;
    return c.f;
}
__device__ __forceinline__ float samp4(const float* __restrict__ img, int yi, int xi) {
    bool valid = (xi >= 0) && (xi < 4) && (yi >= 0) && (yi < 4);
    int idx = min(max(yi, 0), 3) * 4 + min(max(xi, 0), 3);
    return valid ? img[idx] : 0.f;
}

// ---------------- K0: weight transposes ----------------
__global__ __launch_bounds__(256) void k0_tr(
        const float* __restrict__ in_w, const float* __restrict__ mow,
        const float* __restrict__ out_w, const float* __restrict__ q_w,
        const float* __restrict__ k_w, const float* __restrict__ v_w,
        float* __restrict__ WqT, float* __restrict__ mowT,
        float* __restrict__ owT, float* __restrict__ qwT,
        float* __restrict__ kwT, float* __restrict__ vwT) {
    int idx = blockIdx.x * 256 + threadIdx.x;
    if (idx < 65536) {
        int d = idx >> 8, o = idx & 255;
        WqT[idx] = in_w[o * 256 + d];
    } else if (idx < 131072) {
        int k = idx - 65536; int d = k >> 8, o = k & 255;
        mowT[k] = mow[o * 256 + d];
    } else if (idx < 262144) {
        int k = idx - 131072; int c = k >> 8, o = k & 255;
        owT[k] = out_w[o * 512 + c];
    } else if (idx < 278528) {
        int k = idx - 262144; int ci = k >> 9, ch = k & 511;
        qwT[k] = q_w[ch * 32 + ci];
    } else if (idx < 294912) {
        int k = idx - 278528; int ci = k >> 9, ch = k & 511;
        kwT[k] = k_w[ch * 32 + ci];
    } else if (idx < 311296) {
        int k = idx - 294912; int ci = k >> 9, ch = k & 511;
        vwT[k] = v_w[ch * 32 + ci];
    }
}

// ---------------- K1: kx, vx  [b,16,256] ----------------
__global__ __launch_bounds__(256) void k1_kv(const float* __restrict__ rgb,
        const float* __restrict__ in_w, const float* __restrict__ in_b,
        float* __restrict__ kx, float* __restrict__ vx) {
    int b = blockIdx.x >> 4;
    int tt = blockIdx.x & 15;
    int c = threadIdx.x;
    __shared__ __align__(16) float kvin[DIMC];
    float ang = (float)tt * powf(10000.f, -(float)(c >> 1) * (1.f / 128.f));
    float sv = (c & 1) ? cosf(ang) : sinf(ang);
    kvin[c] = rgb[(b * DIMC + c) * HWT + tt] + sv;
    __syncthreads();
    const float4* x4 = (const float4*)kvin;
    const float4* wk4 = (const float4*)(in_w + (DIMC + c) * DIMC);
    const float4* wv4 = (const float4*)(in_w + (2 * DIMC + c) * DIMC);
    float ak0 = in_b[DIMC + c], ak1 = 0.f, av0 = in_b[2 * DIMC + c], av1 = 0.f;
    #pragma unroll 4
    for (int d4 = 0; d4 < 64; ++d4) {
        float4 x = x4[d4], wk = wk4[d4], wv = wv4[d4];
        ak0 = fmaf(wk.x, x.x, ak0); ak1 = fmaf(wk.y, x.y, ak1);
        ak0 = fmaf(wk.z, x.z, ak0); ak1 = fmaf(wk.w, x.w, ak1);
        av0 = fmaf(wv.x, x.x, av0); av1 = fmaf(wv.y, x.y, av1);
        av0 = fmaf(wv.z, x.z, av0); av1 = fmaf(wv.w, x.w, av1);
    }
    kx[(b * HWT + tt) * DIMC + c] = ak0 + ak1;
    vx[(b * HWT + tt) * DIMC + c] = av0 + av1;
}

// ---------------- K2: 4 rows per block ----------------
__global__ __launch_bounds__(256) void k2_qkv(
        const float* __restrict__ pose_feat, const float* __restrict__ rgb,
        const float* __restrict__ pose_init, const float* __restrict__ in_b,
        const float* __restrict__ WqT, const float* __restrict__ mowT,
        const float* __restrict__ mob, const float* __restrict__ pe_gauss,
        const float* __restrict__ off_w1, const float* __restrict__ off_b1,
        const float* __restrict__ off_w2,
        const float* __restrict__ qwT, const float* __restrict__ kwT,
        const float* __restrict__ vwT,
        const float* __restrict__ kx, const float* __restrict__ vx,
        float* __restrict__ qT, float* __restrict__ kTt, float* __restrict__ vT,
        float* __restrict__ vgrid_g) {
    int b = blockIdx.x >> 6;
    int n0 = (blockIdx.x & 63) * 4;
    int t = threadIdx.x;
    __shared__ __align__(16) float xs[4][DIMC];
    __shared__ __align__(16) float qxs[4][DIMC];
    __shared__ __align__(16) float ctx[4][DIMC];
    __shared__ __align__(16) float x2[4][DIMC];
    __shared__ float lg[4][128], psm[4][128];
    __shared__ float qls[4][INNER];
    __shared__ float kvs[4][DIMC];
    __shared__ float vg[4][GROUPS][2];
    __shared__ float g01[4][2];

    if (t < 8) {
        int r = t >> 1, comp = t & 1;
        g01[r][comp] = 2.f * pose_init[(b * 2 + comp) * NQ + n0 + r] - 1.f;
    }
    float4 pf4 = *(const float4*)(pose_feat + (b * DIMC + t) * NQ + n0);
    float pfv[4] = {pf4.x, pf4.y, pf4.z, pf4.w};
    __syncthreads();
    {
        int j = t & 127;
        float pj0 = pe_gauss[j], pj1 = pe_gauss[128 + j];
        #pragma unroll
        for (int r = 0; r < 4; ++r) {
            float cc = (g01[r][0] * pj0 + g01[r][1] * pj1) * 6.28318530717958648f;
            float sc = (t < 128) ? sinf(cc) : cosf(cc);
            xs[r][t] = pfv[r] + sc;
        }
    }
    __syncthreads();
    {
        float bq = in_b[t];
        float a0 = bq, a1 = bq, a2 = bq, a3 = bq;
        #pragma unroll 2
        for (int d4 = 0; d4 < 64; ++d4) {
            int d = d4 * 4;
            float w0 = WqT[(d + 0) * DIMC + t];
            float w1 = WqT[(d + 1) * DIMC + t];
            float w2 = WqT[(d + 2) * DIMC + t];
            float w3 = WqT[(d + 3) * DIMC + t];
            float4 x0 = *(const float4*)&xs[0][d];
            float4 x1 = *(const float4*)&xs[1][d];
            float4 x2_ = *(const float4*)&xs[2][d];
            float4 x3 = *(const float4*)&xs[3][d];
            a0 = fmaf(w0, x0.x, a0); a0 = fmaf(w1, x0.y, a0); a0 = fmaf(w2, x0.z, a0); a0 = fmaf(w3, x0.w, a0);
            a1 = fmaf(w0, x1.x, a1); a1 = fmaf(w1, x1.y, a1); a1 = fmaf(w2, x1.z, a1); a1 = fmaf(w3, x1.w, a1);
            a2 = fmaf(w0, x2_.x, a2); a2 = fmaf(w1, x2_.y, a2); a2 = fmaf(w2, x2_.z, a2); a2 = fmaf(w3, x2_.w, a2);
            a3 = fmaf(w0, x3.x, a3); a3 = fmaf(w1, x3.y, a3); a3 = fmaf(w2, x3.z, a3); a3 = fmaf(w3, x3.w, a3);
        }
        qxs[0][t] = a0; qxs[1][t] = a1; qxs[2][t] = a2; qxs[3][t] = a3;
    }
    __syncthreads();
    #pragma unroll
    for (int rep = 0; rep < 2; ++rep) {
        int idx = rep * 256 + t;
        int r = idx >> 7, hh = (idx >> 4) & 7, tt = idx & 15;
        const float4* kp = (const float4*)(kx + (b * HWT + tt) * DIMC + hh * HDX);
        const float4* qp = (const float4*)(&qxs[r][hh * HDX]);
        float a = 0.f;
        #pragma unroll
        for (int d4 = 0; d4 < 8; ++d4) {
            float4 k4 = kp[d4], q4 = qp[d4];
            a = fmaf(q4.x, k4.x, a); a = fmaf(q4.y, k4.y, a);
            a = fmaf(q4.z, k4.z, a); a = fmaf(q4.w, k4.w, a);
        }
        lg[r][hh * 16 + tt] = a * 0.17677669529663689f;
    }
    __syncthreads();
    if (t < 32) {
        int r = t >> 3, hh = t & 7;
        float m = -1e30f;
        for (int tt = 0; tt < 16; ++tt) m = fmaxf(m, lg[r][hh * 16 + tt]);
        float s = 0.f;
        for (int tt = 0; tt < 16; ++tt) {
            float e = __expf(lg[r][hh * 16 + tt] - m);
            psm[r][hh * 16 + tt] = e; s += e;
        }
        float rr = 1.f / s;
        for (int tt = 0; tt < 16; ++tt) psm[r][hh * 16 + tt] *= rr;
    }
    __syncthreads();
    {
        int hh = t >> 5;
        const float* vp = vx + b * HWT * DIMC + t;
        float a0 = 0.f, a1 = 0.f, a2 = 0.f, a3 = 0.f;
        #pragma unroll
        for (int tt = 0; tt < 16; ++tt) {
            float vv = vp[tt * DIMC];
            a0 = fmaf(psm[0][hh * 16 + tt], vv, a0);
            a1 = fmaf(psm[1][hh * 16 + tt], vv, a1);
            a2 = fmaf(psm[2][hh * 16 + tt], vv, a2);
            a3 = fmaf(psm[3][hh * 16 + tt], vv, a3);
        }
        ctx[0][t] = a0; ctx[1][t] = a1; ctx[2][t] = a2; ctx[3][t] = a3;
    }
    __syncthreads();
    {
        float bm = mob[t];
        float a0 = bm, a1 = bm, a2 = bm, a3 = bm;
        #pragma unroll 2
        for (int d4 = 0; d4 < 64; ++d4) {
            int d = d4 * 4;
            float w0 = mowT[(d + 0) * DIMC + t];
            float w1 = mowT[(d + 1) * DIMC + t];
            float w2 = mowT[(d + 2) * DIMC + t];
            float w3 = mowT[(d + 3) * DIMC + t];
            float4 c0 = *(const float4*)&ctx[0][d];
            float4 c1 = *(const float4*)&ctx[1][d];
            float4 c2 = *(const float4*)&ctx[2][d];
            float4 c3 = *(const float4*)&ctx[3][d];
            a0 = fmaf(w0, c0.x, a0); a0 = fmaf(w1, c0.y, a0); a0 = fmaf(w2, c0.z, a0); a0 = fmaf(w3, c0.w, a0);
            a1 = fmaf(w0, c1.x, a1); a1 = fmaf(w1, c1.y, a1); a1 = fmaf(w2, c1.z, a1); a1 = fmaf(w3, c1.w, a1);
            a2 = fmaf(w0, c2.x, a2); a2 = fmaf(w1, c2.y, a2); a2 = fmaf(w2, c2.z, a2); a2 = fmaf(w3, c2.w, a2);
            a3 = fmaf(w0, c3.x, a3); a3 = fmaf(w1, c3.y, a3); a3 = fmaf(w2, c3.z, a3); a3 = fmaf(w3, c3.w, a3);
        }
        x2[0][t] = pfv[0] + a0; x2[1][t] = pfv[1] + a1;
        x2[2][t] = pfv[2] + a2; x2[3][t] = pfv[3] + a3;
    }
    __syncthreads();
    #pragma unroll
    for (int rep = 0; rep < 2; ++rep) {
        int ch = rep * 256 + t;
        int g = ch >> 6;
        float aq[4] = {0.f, 0.f, 0.f, 0.f};
        #pragma unroll
        for (int ci = 0; ci < 32; ++ci) {
            float w = qwT[ci * INNER + ch];
            aq[0] = fmaf(w, x2[0][g * 32 + ci], aq[0]);
            aq[1] = fmaf(w, x2[1][g * 32 + ci], aq[1]);
            aq[2] = fmaf(w, x2[2][g * 32 + ci], aq[2]);
            aq[3] = fmaf(w, x2[3][g * 32 + ci], aq[3]);
        }
        #pragma unroll
        for (int r = 0; r < 4; ++r) {
            qls[r][ch] = aq[r];
            qT[(b * NQ + n0 + r) * INNER + ch] = aq[r];
        }
    }
    __syncthreads();
    {
        int pr = t >> 3, l = t & 7;
        int r = pr >> 3, g = pr & 7;
        float s0 = 0.f, s1 = 0.f;
        #pragma unroll
        for (int e = 0; e < 8; ++e) {
            int jj = l * 8 + e;
            float ev = gelu_exact(fmaf(qls[r][g * 64 + jj], off_w1[jj], off_b1[jj]));
            s0 = fmaf(ev, off_w2[jj], s0);
            s1 = fmaf(ev, off_w2[64 + jj], s1);
        }
        #pragma unroll
        for (int o = 4; o > 0; o >>= 1) {
            s0 += __shfl_xor(s0, o, 64);
            s1 += __shfl_xor(s1, o, 64);
        }
        if (l == 0) {
            float vgx = g01[r][0] + tanhf(s0) * (2.f / 3.f);
            float vgy = g01[r][1] + tanhf(s1) * (2.f / 3.f);
            vg[r][g][0] = vgx; vg[r][g][1] = vgy;
            float* vp = vgrid_g + ((b * GROUPS + g) * NQ + n0 + r) * 2;
            vp[0] = vgx; vp[1] = vgy;
        }
    }
    __syncthreads();
    #pragma unroll
    for (int rep = 0; rep < 4; ++rep) {
        int idx = rep * 256 + t;
        int r = idx >> 8, c = idx & 255, g = c >> 5;
        float x = (vg[r][g][0] + 1.f) * 2.f - 0.5f;
        float y = (vg[r][g][1] + 1.f) * 2.f - 0.5f;
        float x0f = floorf(x), y0f = floorf(y);
        float wx = x - x0f, wy = y - y0f;
        int x0 = (int)x0f, y0 = (int)y0f;
        const float* img = rgb + (b * DIMC + c) * HWT;
        float v00 = samp4(img, y0, x0), v01 = samp4(img, y0, x0 + 1);
        float v10 = samp4(img, y0 + 1, x0), v11 = samp4(img, y0 + 1, x0 + 1);
        kvs[r][c] = v00 * (1.f - wx) * (1.f - wy) + v01 * wx * (1.f - wy)
                  + v10 * (1.f - wx) * wy + v11 * wx * wy;
    }
    __syncthreads();
    // grouped k/v convs; K transposed [bg][d][n], V row-major [b][n][inner]
    #pragma unroll
    for (int rep = 0; rep < 2; ++rep) {
        int ch = rep * 256 + t;
        int g = ch >> 6;
        float ak[4] = {0.f, 0.f, 0.f, 0.f};
        float av[4] = {0.f, 0.f, 0.f, 0.f};
        #pragma unroll
        for (int ci = 0; ci < 32; ++ci) {
            float wk = kwT[ci * INNER + ch];
            float wv = vwT[ci * INNER + ch];
            #pragma unroll
            for (int r = 0; r < 4; ++r) {
                float x = kvs[r][g * 32 + ci];
                ak[r] = fmaf(wk, x, ak[r]);
                av[r] = fmaf(wv, x, av[r]);
            }
        }
        int hh = ch >> 6, dh = ch & 63;
        float4 kk; kk.x = ak[0]; kk.y = ak[1]; kk.z = ak[2]; kk.w = ak[3];
        *(float4*)(kTt + ((b * HEADS + hh) * DH + dh) * NQ + n0) = kk;
        #pragma unroll
        for (int r = 0; r < 4; ++r)
            vT[(b * NQ + n0 + r) * INNER + ch] = av[r];
    }
}

// ---------------- K3a: CPB bias via MFMA ----------------
__global__ __launch_bounds__(256) void k3a_bias(
        const float* __restrict__ pose_init, const float* __restrict__ vgrid_g,
        const float* __restrict__ w0, const float* __restrict__ b0,
        const float* __restrict__ w1, const float* __restrict__ b1,
        const float* __restrict__ w2, const float* __restrict__ b2,
        ushort_t* __restrict__ bias) {
    int bg = blockIdx.x >> 4;
    int jt = blockIdx.x & 15;
    int b = bg >> 3;
    int tid = threadIdx.x;
    int wv = tid >> 6, lane = tid & 63;
    int lgp = lane >> 4, lr = lane & 15;

    __shared__ float gx_s[NQ], gy_s[NQ];
    gx_s[tid] = 2.f * pose_init[(b * 2 + 0) * NQ + tid] - 1.f;
    gy_s[tid] = 2.f * pose_init[(b * 2 + 1) * NQ + tid] - 1.f;
    __syncthreads();

    float w0a[2][8], w0b[2][8], b0r[2][8];
    short8v bw1[2][4];
    float b1r[4], w2r[4];
    #pragma unroll
    for (int kc = 0; kc < 2; ++kc)
        #pragma unroll
        for (int e = 0; e < 8; ++e) {
            int c = kc * 32 + lgp * 8 + e;
            w0a[kc][e] = w0[2 * c];
            w0b[kc][e] = w0[2 * c + 1];
            b0r[kc][e] = b0[c];
        }
    #pragma unroll
    for (int nt = 0; nt < 4; ++nt) {
        int c2 = nt * 16 + lr;
        b1r[nt] = b1[c2];
        w2r[nt] = w2[c2];
        #pragma unroll
        for (int kc = 0; kc < 2; ++kc)
            #pragma unroll
            for (int e = 0; e < 8; ++e)
                bw1[kc][nt][e] = f2bf(w1[c2 * 64 + kc * 32 + lgp * 8 + e]);
    }
    float b2v = b2[0];

    int j0 = jt * 16 + wv * 4;
    const float* vgp = vgrid_g + bg * NQ * 2;
    #pragma unroll 1
    for (int it = 0; it < 16; ++it) {
        int i = it * 16 + lr;
        float gxi = gx_s[i], gyi = gy_s[i];
        #pragma unroll 1
        for (int jj = 0; jj < 4; ++jj) {
            int j = j0 + jj;
            float vgx = vgp[j * 2], vgy = vgp[j * 2 + 1];
            float px = gxi - vgx, py = gyi - vgy;
            float u = copysignf(__logf(1.f + fabsf(px)), px);
            float vvl = copysignf(__logf(1.f + fabsf(py)), py);
            short8v a0, a1;
            #pragma unroll
            for (int e = 0; e < 8; ++e) {
                float h = fmaf(w0a[0][e], u, fmaf(w0b[0][e], vvl, b0r[0][e]));
                a0[e] = f2bf(fmaxf(h, 0.f));
            }
            #pragma unroll
            for (int e = 0; e < 8; ++e) {
                float h = fmaf(w0a[1][e], u, fmaf(w0b[1][e], vvl, b0r[1][e]));
                a1[e] = f2bf(fmaxf(h, 0.f));
            }
            f32x4 acc0 = {0.f, 0.f, 0.f, 0.f};
            f32x4 acc1 = {0.f, 0.f, 0.f, 0.f};
            f32x4 acc2 = {0.f, 0.f, 0.f, 0.f};
            f32x4 acc3 = {0.f, 0.f, 0.f, 0.f};
            acc0 = __builtin_amdgcn_mfma_f32_16x16x32_bf16(a0, bw1[0][0], acc0, 0, 0, 0);
            acc0 = __builtin_amdgcn_mfma_f32_16x16x32_bf16(a1, bw1[1][0], acc0, 0, 0, 0);
            acc1 = __builtin_amdgcn_mfma_f32_16x16x32_bf16(a0, bw1[0][1], acc1, 0, 0, 0);
            acc1 = __builtin_amdgcn_mfma_f32_16x16x32_bf16(a1, bw1[1][1], acc1, 0, 0, 0);
            acc2 = __builtin_amdgcn_mfma_f32_16x16x32_bf16(a0, bw1[0][2], acc2, 0, 0, 0);
            acc2 = __builtin_amdgcn_mfma_f32_16x16x32_bf16(a1, bw1[1][2], acc2, 0, 0, 0);
            acc3 = __builtin_amdgcn_mfma_f32_16x16x32_bf16(a0, bw1[0][3], acc3, 0, 0, 0);
            acc3 = __builtin_amdgcn_mfma_f32_16x16x32_bf16(a1, bw1[1][3], acc3, 0, 0, 0);
            #pragma unroll
            for (int r = 0; r < 4; ++r) {
                float s = fmaxf(acc0[r] + b1r[0], 0.f) * w2r[0]
                        + fmaxf(acc1[r] + b1r[1], 0.f) * w2r[1]
                        + fmaxf(acc2[r] + b1r[2], 0.f) * w2r[2]
                        + fmaxf(acc3[r] + b1r[3], 0.f) * w2r[3];
                s += __shfl_xor(s, 1, 64);
                s += __shfl_xor(s, 2, 64);
                s += __shfl_xor(s, 4, 64);
                s += __shfl_xor(s, 8, 64);
                if (lr == 0)
                    bias[(bg * NQ + it * 16 + lgp * 4 + r) * NQ + j] = (ushort_t)f2bf(s + b2v);
            }
        }
    }
}

// ---------------- K3b: sim + bias + softmax + attn@V ----------------
// sim: thread = (jq = t&63 -> j quad, ih = t>>6 -> rows ih, ih+4); K in [d][j].
// PV:  thread = (lane = t&31 -> d pair, il = t>>5 -> row); V in [n][d].
__global__ __launch_bounds__(256) void k3b_attn(
        const float* __restrict__ qT, const float* __restrict__ kTt,
        const float* __restrict__ vT, const ushort_t* __restrict__ bias,
        float* __restrict__ aoT) {
    int bg = blockIdx.x >> 5;
    int itile = blockIdx.x & 31;
    int b = bg >> 3, h = bg & 7;
    int i0 = itile * 8;
    int tid = threadIdx.x;

    __shared__ __align__(16) float q_s[8][64];
    __shared__ __align__(16) float attn_s[8][NQ];
    __shared__ float ssum_s[8];

    for (int idx = tid; idx < 8 * 64; idx += 256) {
        int i = idx >> 6, d = idx & 63;
        q_s[i][d] = qT[(b * NQ + i0 + i) * INNER + h * 64 + d] * 0.125f;
    }
    __syncthreads();

    // ---- sim + bias ----
    {
        int jq = tid & 63, ih = tid >> 6;
        const float4* kb4 = (const float4*)(kTt + bg * DH * NQ) + jq;
        float4 s0 = {0.f, 0.f, 0.f, 0.f};
        float4 s1 = {0.f, 0.f, 0.f, 0.f};
        #pragma unroll 4
        for (int d = 0; d < 64; ++d) {
            float4 kv = kb4[d * 64];
            float q0 = q_s[ih][d], q1 = q_s[ih + 4][d];
            s0.x = fmaf(q0, kv.x, s0.x); s0.y = fmaf(q0, kv.y, s0.y);
            s0.z = fmaf(q0, kv.z, s0.z); s0.w = fmaf(q0, kv.w, s0.w);
            s1.x = fmaf(q1, kv.x, s1.x); s1.y = fmaf(q1, kv.y, s1.y);
            s1.z = fmaf(q1, kv.z, s1.z); s1.w = fmaf(q1, kv.w, s1.w);
        }
        uint2 bb0 = *(const uint2*)(bias + (bg * NQ + i0 + ih) * NQ + jq * 4);
        uint2 bb1 = *(const uint2*)(bias + (bg * NQ + i0 + ih + 4) * NQ + jq * 4);
        s0.x += bf2f(bb0.x & 0xffffu); s0.y += bf2f(bb0.x >> 16);
        s0.z += bf2f(bb0.y & 0xffffu); s0.w += bf2f(bb0.y >> 16);
        s1.x += bf2f(bb1.x & 0xffffu); s1.y += bf2f(bb1.x >> 16);
        s1.z += bf2f(bb1.y & 0xffffu); s1.w += bf2f(bb1.y >> 16);
        *(float4*)&attn_s[ih][jq * 4] = s0;
        *(float4*)&attn_s[ih + 4][jq * 4] = s1;
    }
    __syncthreads();
    // ---- softmax (unnormalized; divide in PV) ----
    {
        int il = tid >> 5, lane = tid & 31;
        float m = -1e30f;
        for (int jj = 0; jj < 8; ++jj) m = fmaxf(m, attn_s[il][jj * 32 + lane]);
        #pragma unroll
        for (int o = 16; o > 0; o >>= 1) m = fmaxf(m, __shfl_xor(m, o, 32));
        float s = 0.f;
        for (int jj = 0; jj < 8; ++jj) {
            int j = jj * 32 + lane;
            float e = __expf(attn_s[il][j] - m);
            attn_s[il][j] = e;
            s += e;
        }
        #pragma unroll
        for (int o = 16; o > 0; o >>= 1) s += __shfl_xor(s, o, 32);
        if (lane == 0) ssum_s[il] = s;
    }
    __syncthreads();
    // ---- PV: coalesced over V rows ----
    {
        int lane = tid & 31, il = tid >> 5;
        const float2* vp = (const float2*)(vT + b * NQ * INNER + h * 64) + lane;
        float a0 = 0.f, a1 = 0.f, c0 = 0.f, c1 = 0.f;
        #pragma unroll 4
        for (int j = 0; j < NQ; j += 2) {
            float w0 = attn_s[il][j], w1 = attn_s[il][j + 1];
            float2 v0 = vp[j * (INNER / 2)];
            float2 v1 = vp[(j + 1) * (INNER / 2)];
            a0 = fmaf(w0, v0.x, a0); a1 = fmaf(w0, v0.y, a1);
            c0 = fmaf(w1, v1.x, c0); c1 = fmaf(w1, v1.y, c1);
        }
        float r = 1.f / ssum_s[il];
        float2 res; res.x = (a0 + c0) * r; res.y = (a1 + c1) * r;
        *(float2*)(aoT + (b * NQ + i0 + il) * INNER + h * 64 + lane * 2) = res;
    }
}

// ---------------- K4: final projection 512 -> 256 (coalesced owT) ----------------
__global__ __launch_bounds__(256) void k4_proj(const float* __restrict__ aoT,
        const float* __restrict__ owT, const float* __restrict__ out_b,
        float* __restrict__ out) {
    int b = blockIdx.x >> 6;
    int n0 = (blockIdx.x & 63) * 4;
    int t = threadIdx.x;
    __shared__ __align__(16) float xl[4][INNER];
    for (int idx = t; idx < 4 * INNER; idx += 256) {
        xl[idx >> 9][idx & 511] = aoT[(b * NQ + n0) * INNER + idx];
    }
    __syncthreads();
    float bo = out_b[t];
    float a0 = bo, a1 = bo, a2 = bo, a3 = bo;
    #pragma unroll 2
    for (int c4 = 0; c4 < 128; ++c4) {
        int c = c4 * 4;
        float w0 = owT[(c + 0) * DIMC + t];
        float w1 = owT[(c + 1) * DIMC + t];
        float w2 = owT[(c + 2) * DIMC + t];
        float w3 = owT[(c + 3) * DIMC + t];
        float4 x0 = *(const float4*)&xl[0][c];
        float4 x1 = *(const float4*)&xl[1][c];
        float4 x2 = *(const float4*)&xl[2][c];
        float4 x3 = *(const float4*)&xl[3][c];
        a0 = fmaf(w0, x0.x, a0); a0 = fmaf(w1, x0.y, a0); a0 = fmaf(w2, x0.z, a0); a0 = fmaf(w3, x0.w, a0);
        a1 = fmaf(w0, x1.x, a1); a1 = fmaf(w1, x1.y, a1); a1 = fmaf(w2, x1.z, a1); a1 = fmaf(w3, x1.w, a1);
        a2 = fmaf(w0, x2.x, a2); a2 = fmaf(w1, x2.y, a2); a2 = fmaf(w2, x2.z, a2); a2 = fmaf(w3, x2.w, a2);
        a3 = fmaf(w0, x3.x, a3); a3 = fmaf(w1, x3.y, a3); a3 = fmaf(w2, x3.z, a3); a3 = fmaf(w3, x3.w, a3);
    }
    float4 res; res.x = a0; res.y = a1; res.z = a2; res.w = a3;
    *(float4*)(out + (b * DIMC + t) * NQ + n0) = res;
}

extern "C" void kernel_launch(void* const* d_in, const int* in_sizes, int n_in,
                              void* d_out, int out_size, void* d_ws, size_t ws_size,
                              hipStream_t stream) {
    const float* pose_feat = (const float*)d_in[0];
    const float* rgb       = (const float*)d_in[1];
    const float* pose_init = (const float*)d_in[2];
    const float* mha_in_w  = (const float*)d_in[3];
    const float* mha_in_b  = (const float*)d_in[4];
    const float* mha_out_w = (const float*)d_in[5];
    const float* mha_out_b = (const float*)d_in[6];
    const float* pe_gauss  = (const float*)d_in[7];
    const float* off_w1    = (const float*)d_in[8];
    const float* off_b1    = (const float*)d_in[9];
    const float* off_w2    = (const float*)d_in[10];
    const float* cpb_w0    = (const float*)d_in[11];
    const float* cpb_b0    = (const float*)d_in[12];
    const float* cpb_w1    = (const float*)d_in[13];
    const float* cpb_b1    = (const float*)d_in[14];
    const float* cpb_w2    = (const float*)d_in[15];
    const float* cpb_b2    = (const float*)d_in[16];
    const float* q_w       = (const float*)d_in[17];
    const float* k_w       = (const float*)d_in[18];
    const float* v_w       = (const float*)d_in[19];
    const float* out_w     = (const float*)d_in[20];
    const float* out_b     = (const float*)d_in[21];

    float* ws    = (float*)d_ws;
    float* kx    = ws;                     // 16384
    float* vx    = kx + 16384;             // 16384
    float* qT    = vx + 16384;             // 524288
    float* kTt   = qT + 524288;            // 524288
    float* vT    = kTt + 524288;           // 524288
    float* vgrid = vT + 524288;            // 16384
    float* aoT   = vgrid + 16384;          // 524288
    float* WqT   = aoT + 524288;           // 65536
    float* mowT  = WqT + 65536;            // 65536
    float* owT   = mowT + 65536;           // 131072
    float* qwT   = owT + 131072;           // 16384
    float* kwT   = qwT + 16384;            // 16384
    float* vwT   = kwT + 16384;            // 16384
    ushort_t* bias = (ushort_t*)(vwT + 16384);   // 32*256*256 bf16 = 4 MB
    float* out   = (float*)d_out;

    k0_tr<<<1216, 256, 0, stream>>>(mha_in_w, mha_out_w, out_w, q_w, k_w, v_w,
        WqT, mowT, owT, qwT, kwT, vwT);
    k1_kv<<<64, 256, 0, stream>>>(rgb, mha_in_w, mha_in_b, kx, vx);
    k2_qkv<<<256, 256, 0, stream>>>(pose_feat, rgb, pose_init, mha_in_b,
        WqT, mowT, mha_out_b, pe_gauss, off_w1, off_b1, off_w2, qwT, kwT, vwT,
        kx, vx, qT, kTt, vT, vgrid);
    k3a_bias<<<512, 256, 0, stream>>>(pose_init, vgrid,
        cpb_w0, cpb_b0, cpb_w1, cpb_b1, cpb_w2, cpb_b2, bias);
    k3b_attn<<<1024, 256, 0, stream>>>(qT, kTt, vT, bias, aoT);
    k4_proj<<<256, 256, 0, stream>>>(aoT, owT, out_b, out);
}

// Round 8
// 190.103 us; speedup vs baseline: 1.6388x; 1.0999x over previous
//
#include <hip/hip_runtime.h>
#include <hip/hip_bf16.h>
#include <math.h>

// DeformableAttention2D — round 7 kernel (resubmit after infra failure):
// k3a occupancy fix (grid 512->2048, 4-way i-split) + compiler-packed bf16
// cvt in the A-fragment. k3b/k2 etc unchanged.
// Sizes (fixed): B=4, N=256, DIM=256, HEADS=8, GROUPS=8, INNER=512, DH=64,
// cross-attn head dim 32, rgb 4x4 (16 tokens), CPB MLP 2->64->64->1.

#define DIMC 256
#define NQ 256
#define HEADS 8
#define GROUPS 8
#define INNER 512
#define DH 64
#define HDX 32
#define HWT 16

typedef __attribute__((ext_vector_type(8))) short short8v;
typedef __attribute__((ext_vector_type(4))) float f32x4;
typedef unsigned short ushort_t;

__device__ __forceinline__ float gelu_exact(float x) {
    return 0.5f * x * (1.f + erff(x * 0.70710678118654752f));
}
__device__ __forceinline__ short f2bf(float x) {
    union { float f; unsigned u; } c; c.f = x;
    unsigned r = c.u + 0x7fffu + ((c.u >> 16) & 1u);
    return (short)(r >> 16);
}
__device__ __forceinline__ short f2bf_hw(float x) {   // via HW cvt (packs to v_cvt_pk_bf16_f32)
    return (short)__bfloat16_as_ushort(__float2bfloat16(x));
}
__device__ __forceinline__ float bf2f(unsigned hbits) {
    union { unsigned u; float f; } c; c.u = hbits << 16;
    return c.f;
}
__device__ __forceinline__ float samp4(const float* __restrict__ img, int yi, int xi) {
    bool valid = (xi >= 0) && (xi < 4) && (yi >= 0) && (yi < 4);
    int idx = min(max(yi, 0), 3) * 4 + min(max(xi, 0), 3);
    return valid ? img[idx] : 0.f;
}

// ---------------- K0: weight transposes ----------------
__global__ __launch_bounds__(256) void k0_tr(
        const float* __restrict__ in_w, const float* __restrict__ mow,
        const float* __restrict__ out_w, const float* __restrict__ q_w,
        const float* __restrict__ k_w, const float* __restrict__ v_w,
        float* __restrict__ WqT, float* __restrict__ mowT,
        float* __restrict__ owT, float* __restrict__ qwT,
        float* __restrict__ kwT, float* __restrict__ vwT) {
    int idx = blockIdx.x * 256 + threadIdx.x;
    if (idx < 65536) {
        int d = idx >> 8, o = idx & 255;
        WqT[idx] = in_w[o * 256 + d];
    } else if (idx < 131072) {
        int k = idx - 65536; int d = k >> 8, o = k & 255;
        mowT[k] = mow[o * 256 + d];
    } else if (idx < 262144) {
        int k = idx - 131072; int c = k >> 8, o = k & 255;
        owT[k] = out_w[o * 512 + c];
    } else if (idx < 278528) {
        int k = idx - 262144; int ci = k >> 9, ch = k & 511;
        qwT[k] = q_w[ch * 32 + ci];
    } else if (idx < 294912) {
        int k = idx - 278528; int ci = k >> 9, ch = k & 511;
        kwT[k] = k_w[ch * 32 + ci];
    } else if (idx < 311296) {
        int k = idx - 294912; int ci = k >> 9, ch = k & 511;
        vwT[k] = v_w[ch * 32 + ci];
    }
}

// ---------------- K1: kx, vx  [b,16,256] ----------------
__global__ __launch_bounds__(256) void k1_kv(const float* __restrict__ rgb,
        const float* __restrict__ in_w, const float* __restrict__ in_b,
        float* __restrict__ kx, float* __restrict__ vx) {
    int b = blockIdx.x >> 4;
    int tt = blockIdx.x & 15;
    int c = threadIdx.x;
    __shared__ __align__(16) float kvin[DIMC];
    float ang = (float)tt * powf(10000.f, -(float)(c >> 1) * (1.f / 128.f));
    float sv = (c & 1) ? cosf(ang) : sinf(ang);
    kvin[c] = rgb[(b * DIMC + c) * HWT + tt] + sv;
    __syncthreads();
    const float4* x4 = (const float4*)kvin;
    const float4* wk4 = (const float4*)(in_w + (DIMC + c) * DIMC);
    const float4* wv4 = (const float4*)(in_w + (2 * DIMC + c) * DIMC);
    float ak0 = in_b[DIMC + c], ak1 = 0.f, av0 = in_b[2 * DIMC + c], av1 = 0.f;
    #pragma unroll 4
    for (int d4 = 0; d4 < 64; ++d4) {
        float4 x = x4[d4], wk = wk4[d4], wv = wv4[d4];
        ak0 = fmaf(wk.x, x.x, ak0); ak1 = fmaf(wk.y, x.y, ak1);
        ak0 = fmaf(wk.z, x.z, ak0); ak1 = fmaf(wk.w, x.w, ak1);
        av0 = fmaf(wv.x, x.x, av0); av1 = fmaf(wv.y, x.y, av1);
        av0 = fmaf(wv.z, x.z, av0); av1 = fmaf(wv.w, x.w, av1);
    }
    kx[(b * HWT + tt) * DIMC + c] = ak0 + ak1;
    vx[(b * HWT + tt) * DIMC + c] = av0 + av1;
}

// ---------------- K2: 4 rows per block ----------------
__global__ __launch_bounds__(256) void k2_qkv(
        const float* __restrict__ pose_feat, const float* __restrict__ rgb,
        const float* __restrict__ pose_init, const float* __restrict__ in_b,
        const float* __restrict__ WqT, const float* __restrict__ mowT,
        const float* __restrict__ mob, const float* __restrict__ pe_gauss,
        const float* __restrict__ off_w1, const float* __restrict__ off_b1,
        const float* __restrict__ off_w2,
        const float* __restrict__ qwT, const float* __restrict__ kwT,
        const float* __restrict__ vwT,
        const float* __restrict__ kx, const float* __restrict__ vx,
        float* __restrict__ qT, float* __restrict__ kTt, float* __restrict__ vT,
        float* __restrict__ vgrid_g) {
    int b = blockIdx.x >> 6;
    int n0 = (blockIdx.x & 63) * 4;
    int t = threadIdx.x;
    __shared__ __align__(16) float xs[4][DIMC];
    __shared__ __align__(16) float qxs[4][DIMC];
    __shared__ __align__(16) float ctx[4][DIMC];
    __shared__ __align__(16) float x2[4][DIMC];
    __shared__ float lg[4][128], psm[4][128];
    __shared__ float qls[4][INNER];
    __shared__ float kvs[4][DIMC];
    __shared__ float vg[4][GROUPS][2];
    __shared__ float g01[4][2];

    if (t < 8) {
        int r = t >> 1, comp = t & 1;
        g01[r][comp] = 2.f * pose_init[(b * 2 + comp) * NQ + n0 + r] - 1.f;
    }
    float4 pf4 = *(const float4*)(pose_feat + (b * DIMC + t) * NQ + n0);
    float pfv[4] = {pf4.x, pf4.y, pf4.z, pf4.w};
    __syncthreads();
    {
        int j = t & 127;
        float pj0 = pe_gauss[j], pj1 = pe_gauss[128 + j];
        #pragma unroll
        for (int r = 0; r < 4; ++r) {
            float cc = (g01[r][0] * pj0 + g01[r][1] * pj1) * 6.28318530717958648f;
            float sc = (t < 128) ? sinf(cc) : cosf(cc);
            xs[r][t] = pfv[r] + sc;
        }
    }
    __syncthreads();
    {
        float bq = in_b[t];
        float a0 = bq, a1 = bq, a2 = bq, a3 = bq;
        #pragma unroll 2
        for (int d4 = 0; d4 < 64; ++d4) {
            int d = d4 * 4;
            float w0 = WqT[(d + 0) * DIMC + t];
            float w1 = WqT[(d + 1) * DIMC + t];
            float w2 = WqT[(d + 2) * DIMC + t];
            float w3 = WqT[(d + 3) * DIMC + t];
            float4 x0 = *(const float4*)&xs[0][d];
            float4 x1 = *(const float4*)&xs[1][d];
            float4 x2_ = *(const float4*)&xs[2][d];
            float4 x3 = *(const float4*)&xs[3][d];
            a0 = fmaf(w0, x0.x, a0); a0 = fmaf(w1, x0.y, a0); a0 = fmaf(w2, x0.z, a0); a0 = fmaf(w3, x0.w, a0);
            a1 = fmaf(w0, x1.x, a1); a1 = fmaf(w1, x1.y, a1); a1 = fmaf(w2, x1.z, a1); a1 = fmaf(w3, x1.w, a1);
            a2 = fmaf(w0, x2_.x, a2); a2 = fmaf(w1, x2_.y, a2); a2 = fmaf(w2, x2_.z, a2); a2 = fmaf(w3, x2_.w, a2);
            a3 = fmaf(w0, x3.x, a3); a3 = fmaf(w1, x3.y, a3); a3 = fmaf(w2, x3.z, a3); a3 = fmaf(w3, x3.w, a3);
        }
        qxs[0][t] = a0; qxs[1][t] = a1; qxs[2][t] = a2; qxs[3][t] = a3;
    }
    __syncthreads();
    #pragma unroll
    for (int rep = 0; rep < 2; ++rep) {
        int idx = rep * 256 + t;
        int r = idx >> 7, hh = (idx >> 4) & 7, tt = idx & 15;
        const float4* kp = (const float4*)(kx + (b * HWT + tt) * DIMC + hh * HDX);
        const float4* qp = (const float4*)(&qxs[r][hh * HDX]);
        float a = 0.f;
        #pragma unroll
        for (int d4 = 0; d4 < 8; ++d4) {
            float4 k4 = kp[d4], q4 = qp[d4];
            a = fmaf(q4.x, k4.x, a); a = fmaf(q4.y, k4.y, a);
            a = fmaf(q4.z, k4.z, a); a = fmaf(q4.w, k4.w, a);
        }
        lg[r][hh * 16 + tt] = a * 0.17677669529663689f;
    }
    __syncthreads();
    if (t < 32) {
        int r = t >> 3, hh = t & 7;
        float m = -1e30f;
        for (int tt = 0; tt < 16; ++tt) m = fmaxf(m, lg[r][hh * 16 + tt]);
        float s = 0.f;
        for (int tt = 0; tt < 16; ++tt) {
            float e = __expf(lg[r][hh * 16 + tt] - m);
            psm[r][hh * 16 + tt] = e; s += e;
        }
        float rr = 1.f / s;
        for (int tt = 0; tt < 16; ++tt) psm[r][hh * 16 + tt] *= rr;
    }
    __syncthreads();
    {
        int hh = t >> 5;
        const float* vp = vx + b * HWT * DIMC + t;
        float a0 = 0.f, a1 = 0.f, a2 = 0.f, a3 = 0.f;
        #pragma unroll
        for (int tt = 0; tt < 16; ++tt) {
            float vv = vp[tt * DIMC];
            a0 = fmaf(psm[0][hh * 16 + tt], vv, a0);
            a1 = fmaf(psm[1][hh * 16 + tt], vv, a1);
            a2 = fmaf(psm[2][hh * 16 + tt], vv, a2);
            a3 = fmaf(psm[3][hh * 16 + tt], vv, a3);
        }
        ctx[0][t] = a0; ctx[1][t] = a1; ctx[2][t] = a2; ctx[3][t] = a3;
    }
    __syncthreads();
    {
        float bm = mob[t];
        float a0 = bm, a1 = bm, a2 = bm, a3 = bm;
        #pragma unroll 2
        for (int d4 = 0; d4 < 64; ++d4) {
            int d = d4 * 4;
            float w0 = mowT[(d + 0) * DIMC + t];
            float w1 = mowT[(d + 1) * DIMC + t];
            float w2 = mowT[(d + 2) * DIMC + t];
            float w3 = mowT[(d + 3) * DIMC + t];
            float4 c0 = *(const float4*)&ctx[0][d];
            float4 c1 = *(const float4*)&ctx[1][d];
            float4 c2 = *(const float4*)&ctx[2][d];
            float4 c3 = *(const float4*)&ctx[3][d];
            a0 = fmaf(w0, c0.x, a0); a0 = fmaf(w1, c0.y, a0); a0 = fmaf(w2, c0.z, a0); a0 = fmaf(w3, c0.w, a0);
            a1 = fmaf(w0, c1.x, a1); a1 = fmaf(w1, c1.y, a1); a1 = fmaf(w2, c1.z, a1); a1 = fmaf(w3, c1.w, a1);
            a2 = fmaf(w0, c2.x, a2); a2 = fmaf(w1, c2.y, a2); a2 = fmaf(w2, c2.z, a2); a2 = fmaf(w3, c2.w, a2);
            a3 = fmaf(w0, c3.x, a3); a3 = fmaf(w1, c3.y, a3); a3 = fmaf(w2, c3.z, a3); a3 = fmaf(w3, c3.w, a3);
        }
        x2[0][t] = pfv[0] + a0; x2[1][t] = pfv[1] + a1;
        x2[2][t] = pfv[2] + a2; x2[3][t] = pfv[3] + a3;
    }
    __syncthreads();
    #pragma unroll
    for (int rep = 0; rep < 2; ++rep) {
        int ch = rep * 256 + t;
        int g = ch >> 6;
        float aq[4] = {0.f, 0.f, 0.f, 0.f};
        #pragma unroll
        for (int ci = 0; ci < 32; ++ci) {
            float w = qwT[ci * INNER + ch];
            aq[0] = fmaf(w, x2[0][g * 32 + ci], aq[0]);
            aq[1] = fmaf(w, x2[1][g * 32 + ci], aq[1]);
            aq[2] = fmaf(w, x2[2][g * 32 + ci], aq[2]);
            aq[3] = fmaf(w, x2[3][g * 32 + ci], aq[3]);
        }
        #pragma unroll
        for (int r = 0; r < 4; ++r) {
            qls[r][ch] = aq[r];
            qT[(b * NQ + n0 + r) * INNER + ch] = aq[r];
        }
    }
    __syncthreads();
    {
        int pr = t >> 3, l = t & 7;
        int r = pr >> 3, g = pr & 7;
        float s0 = 0.f, s1 = 0.f;
        #pragma unroll
        for (int e = 0; e < 8; ++e) {
            int jj = l * 8 + e;
            float ev = gelu_exact(fmaf(qls[r][g * 64 + jj], off_w1[jj], off_b1[jj]));
            s0 = fmaf(ev, off_w2[jj], s0);
            s1 = fmaf(ev, off_w2[64 + jj], s1);
        }
        #pragma unroll
        for (int o = 4; o > 0; o >>= 1) {
            s0 += __shfl_xor(s0, o, 64);
            s1 += __shfl_xor(s1, o, 64);
        }
        if (l == 0) {
            float vgx = g01[r][0] + tanhf(s0) * (2.f / 3.f);
            float vgy = g01[r][1] + tanhf(s1) * (2.f / 3.f);
            vg[r][g][0] = vgx; vg[r][g][1] = vgy;
            float* vp = vgrid_g + ((b * GROUPS + g) * NQ + n0 + r) * 2;
            vp[0] = vgx; vp[1] = vgy;
        }
    }
    __syncthreads();
    #pragma unroll
    for (int rep = 0; rep < 4; ++rep) {
        int idx = rep * 256 + t;
        int r = idx >> 8, c = idx & 255, g = c >> 5;
        float x = (vg[r][g][0] + 1.f) * 2.f - 0.5f;
        float y = (vg[r][g][1] + 1.f) * 2.f - 0.5f;
        float x0f = floorf(x), y0f = floorf(y);
        float wx = x - x0f, wy = y - y0f;
        int x0 = (int)x0f, y0 = (int)y0f;
        const float* img = rgb + (b * DIMC + c) * HWT;
        float v00 = samp4(img, y0, x0), v01 = samp4(img, y0, x0 + 1);
        float v10 = samp4(img, y0 + 1, x0), v11 = samp4(img, y0 + 1, x0 + 1);
        kvs[r][c] = v00 * (1.f - wx) * (1.f - wy) + v01 * wx * (1.f - wy)
                  + v10 * (1.f - wx) * wy + v11 * wx * wy;
    }
    __syncthreads();
    // grouped k/v convs; K transposed [bg][d][n], V row-major [b][n][inner]
    #pragma unroll
    for (int rep = 0; rep < 2; ++rep) {
        int ch = rep * 256 + t;
        int g = ch >> 6;
        float ak[4] = {0.f, 0.f, 0.f, 0.f};
        float av[4] = {0.f, 0.f, 0.f, 0.f};
        #pragma unroll
        for (int ci = 0; ci < 32; ++ci) {
            float wk = kwT[ci * INNER + ch];
            float wv = vwT[ci * INNER + ch];
            #pragma unroll
            for (int r = 0; r < 4; ++r) {
                float x = kvs[r][g * 32 + ci];
                ak[r] = fmaf(wk, x, ak[r]);
                av[r] = fmaf(wv, x, av[r]);
            }
        }
        int hh = ch >> 6, dh = ch & 63;
        float4 kk; kk.x = ak[0]; kk.y = ak[1]; kk.z = ak[2]; kk.w = ak[3];
        *(float4*)(kTt + ((b * HEADS + hh) * DH + dh) * NQ + n0) = kk;
        #pragma unroll
        for (int r = 0; r < 4; ++r)
            vT[(b * NQ + n0 + r) * INNER + ch] = av[r];
    }
}

// ---------------- K3a: CPB bias via MFMA (grid 2048, 4-way i-split) ----------------
// blockIdx = (bg*16 + jt)*4 + itc; wave handles 4 j's, 4 i-tiles of 16.
__global__ __launch_bounds__(256) void k3a_bias(
        const float* __restrict__ pose_init, const float* __restrict__ vgrid_g,
        const float* __restrict__ w0, const float* __restrict__ b0,
        const float* __restrict__ w1, const float* __restrict__ b1,
        const float* __restrict__ w2, const float* __restrict__ b2,
        ushort_t* __restrict__ bias) {
    int bg = blockIdx.x >> 6;
    int jt = (blockIdx.x >> 2) & 15;
    int itc = blockIdx.x & 3;
    int b = bg >> 3;
    int tid = threadIdx.x;
    int wv = tid >> 6, lane = tid & 63;
    int lgp = lane >> 4, lr = lane & 15;

    __shared__ float gx_s[64], gy_s[64];
    if (tid < 64) {
        int i = itc * 64 + tid;
        gx_s[tid] = 2.f * pose_init[(b * 2 + 0) * NQ + i] - 1.f;
        gy_s[tid] = 2.f * pose_init[(b * 2 + 1) * NQ + i] - 1.f;
    }
    __syncthreads();

    float w0a[2][8], w0b[2][8], b0r[2][8];
    short8v bw1[2][4];
    float b1r[4], w2r[4];
    #pragma unroll
    for (int kc = 0; kc < 2; ++kc)
        #pragma unroll
        for (int e = 0; e < 8; ++e) {
            int c = kc * 32 + lgp * 8 + e;
            w0a[kc][e] = w0[2 * c];
            w0b[kc][e] = w0[2 * c + 1];
            b0r[kc][e] = b0[c];
        }
    #pragma unroll
    for (int nt = 0; nt < 4; ++nt) {
        int c2 = nt * 16 + lr;
        b1r[nt] = b1[c2];
        w2r[nt] = w2[c2];
        #pragma unroll
        for (int kc = 0; kc < 2; ++kc)
            #pragma unroll
            for (int e = 0; e < 8; ++e)
                bw1[kc][nt][e] = f2bf(w1[c2 * 64 + kc * 32 + lgp * 8 + e]);
    }
    float b2v = b2[0];

    int j0 = jt * 16 + wv * 4;
    const float* vgp = vgrid_g + bg * NQ * 2;
    // hoist the 4 j-grid points
    float vgxr[4], vgyr[4];
    #pragma unroll
    for (int jj = 0; jj < 4; ++jj) {
        vgxr[jj] = vgp[(j0 + jj) * 2];
        vgyr[jj] = vgp[(j0 + jj) * 2 + 1];
    }

    #pragma unroll 1
    for (int it2 = 0; it2 < 4; ++it2) {
        int it = itc * 4 + it2;
        float gxi = gx_s[it2 * 16 + lr], gyi = gy_s[it2 * 16 + lr];
        #pragma unroll 1
        for (int jj = 0; jj < 4; ++jj) {
            int j = j0 + jj;
            float px = gxi - vgxr[jj], py = gyi - vgyr[jj];
            float u = copysignf(__logf(1.f + fabsf(px)), px);
            float vvl = copysignf(__logf(1.f + fabsf(py)), py);
            short8v a0, a1;
            #pragma unroll
            for (int e = 0; e < 8; ++e) {
                float h = fmaf(w0a[0][e], u, fmaf(w0b[0][e], vvl, b0r[0][e]));
                a0[e] = f2bf_hw(fmaxf(h, 0.f));
            }
            #pragma unroll
            for (int e = 0; e < 8; ++e) {
                float h = fmaf(w0a[1][e], u, fmaf(w0b[1][e], vvl, b0r[1][e]));
                a1[e] = f2bf_hw(fmaxf(h, 0.f));
            }
            f32x4 acc0 = {0.f, 0.f, 0.f, 0.f};
            f32x4 acc1 = {0.f, 0.f, 0.f, 0.f};
            f32x4 acc2 = {0.f, 0.f, 0.f, 0.f};
            f32x4 acc3 = {0.f, 0.f, 0.f, 0.f};
            acc0 = __builtin_amdgcn_mfma_f32_16x16x32_bf16(a0, bw1[0][0], acc0, 0, 0, 0);
            acc0 = __builtin_amdgcn_mfma_f32_16x16x32_bf16(a1, bw1[1][0], acc0, 0, 0, 0);
            acc1 = __builtin_amdgcn_mfma_f32_16x16x32_bf16(a0, bw1[0][1], acc1, 0, 0, 0);
            acc1 = __builtin_amdgcn_mfma_f32_16x16x32_bf16(a1, bw1[1][1], acc1, 0, 0, 0);
            acc2 = __builtin_amdgcn_mfma_f32_16x16x32_bf16(a0, bw1[0][2], acc2, 0, 0, 0);
            acc2 = __builtin_amdgcn_mfma_f32_16x16x32_bf16(a1, bw1[1][2], acc2, 0, 0, 0);
            acc3 = __builtin_amdgcn_mfma_f32_16x16x32_bf16(a0, bw1[0][3], acc3, 0, 0, 0);
            acc3 = __builtin_amdgcn_mfma_f32_16x16x32_bf16(a1, bw1[1][3], acc3, 0, 0, 0);
            #pragma unroll
            for (int r = 0; r < 4; ++r) {
                float s = fmaxf(acc0[r] + b1r[0], 0.f) * w2r[0]
                        + fmaxf(acc1[r] + b1r[1], 0.f) * w2r[1]
                        + fmaxf(acc2[r] + b1r[2], 0.f) * w2r[2]
                        + fmaxf(acc3[r] + b1r[3], 0.f) * w2r[3];
                s += __shfl_xor(s, 1, 64);
                s += __shfl_xor(s, 2, 64);
                s += __shfl_xor(s, 4, 64);
                s += __shfl_xor(s, 8, 64);
                if (lr == 0)
                    bias[(bg * NQ + it * 16 + lgp * 4 + r) * NQ + j] = (ushort_t)f2bf(s + b2v);
            }
        }
    }
}

// ---------------- K3b: sim + bias + softmax + attn@V ----------------
__global__ __launch_bounds__(256) void k3b_attn(
        const float* __restrict__ qT, const float* __restrict__ kTt,
        const float* __restrict__ vT, const ushort_t* __restrict__ bias,
        float* __restrict__ aoT) {
    int bg = blockIdx.x >> 5;
    int itile = blockIdx.x & 31;
    int b = bg >> 3, h = bg & 7;
    int i0 = itile * 8;
    int tid = threadIdx.x;

    __shared__ __align__(16) float q_s[8][64];
    __shared__ __align__(16) float attn_s[8][NQ];
    __shared__ float ssum_s[8];

    for (int idx = tid; idx < 8 * 64; idx += 256) {
        int i = idx >> 6, d = idx & 63;
        q_s[i][d] = qT[(b * NQ + i0 + i) * INNER + h * 64 + d] * 0.125f;
    }
    __syncthreads();

    {
        int jq = tid & 63, ih = tid >> 6;
        const float4* kb4 = (const float4*)(kTt + bg * DH * NQ) + jq;
        float4 s0 = {0.f, 0.f, 0.f, 0.f};
        float4 s1 = {0.f, 0.f, 0.f, 0.f};
        #pragma unroll 4
        for (int d = 0; d < 64; ++d) {
            float4 kv = kb4[d * 64];
            float q0 = q_s[ih][d], q1 = q_s[ih + 4][d];
            s0.x = fmaf(q0, kv.x, s0.x); s0.y = fmaf(q0, kv.y, s0.y);
            s0.z = fmaf(q0, kv.z, s0.z); s0.w = fmaf(q0, kv.w, s0.w);
            s1.x = fmaf(q1, kv.x, s1.x); s1.y = fmaf(q1, kv.y, s1.y);
            s1.z = fmaf(q1, kv.z, s1.z); s1.w = fmaf(q1, kv.w, s1.w);
        }
        uint2 bb0 = *(const uint2*)(bias + (bg * NQ + i0 + ih) * NQ + jq * 4);
        uint2 bb1 = *(const uint2*)(bias + (bg * NQ + i0 + ih + 4) * NQ + jq * 4);
        s0.x += bf2f(bb0.x & 0xffffu); s0.y += bf2f(bb0.x >> 16);
        s0.z += bf2f(bb0.y & 0xffffu); s0.w += bf2f(bb0.y >> 16);
        s1.x += bf2f(bb1.x & 0xffffu); s1.y += bf2f(bb1.x >> 16);
        s1.z += bf2f(bb1.y & 0xffffu); s1.w += bf2f(bb1.y >> 16);
        *(float4*)&attn_s[ih][jq * 4] = s0;
        *(float4*)&attn_s[ih + 4][jq * 4] = s1;
    }
    __syncthreads();
    {
        int il = tid >> 5, lane = tid & 31;
        float m = -1e30f;
        for (int jj = 0; jj < 8; ++jj) m = fmaxf(m, attn_s[il][jj * 32 + lane]);
        #pragma unroll
        for (int o = 16; o > 0; o >>= 1) m = fmaxf(m, __shfl_xor(m, o, 32));
        float s = 0.f;
        for (int jj = 0; jj < 8; ++jj) {
            int j = jj * 32 + lane;
            float e = __expf(attn_s[il][j] - m);
            attn_s[il][j] = e;
            s += e;
        }
        #pragma unroll
        for (int o = 16; o > 0; o >>= 1) s += __shfl_xor(s, o, 32);
        if (lane == 0) ssum_s[il] = s;
    }
    __syncthreads();
    {
        int lane = tid & 31, il = tid >> 5;
        const float2* vp = (const float2*)(vT + b * NQ * INNER + h * 64) + lane;
        float a0 = 0.f, a1 = 0.f, c0 = 0.f, c1 = 0.f;
        #pragma unroll 4
        for (int j = 0; j < NQ; j += 2) {
            float w0 = attn_s[il][j], w1 = attn_s[il][j + 1];
            float2 v0 = vp[j * (INNER / 2)];
            float2 v1 = vp[(j + 1) * (INNER / 2)];
            a0 = fmaf(w0, v0.x, a0); a1 = fmaf(w0, v0.y, a1);
            c0 = fmaf(w1, v1.x, c0); c1 = fmaf(w1, v1.y, c1);
        }
        float r = 1.f / ssum_s[il];
        float2 res; res.x = (a0 + c0) * r; res.y = (a1 + c1) * r;
        *(float2*)(aoT + (b * NQ + i0 + il) * INNER + h * 64 + lane * 2) = res;
    }
}

// ---------------- K4: final projection 512 -> 256 (coalesced owT) ----------------
__global__ __launch_bounds__(256) void k4_proj(const float* __restrict__ aoT,
        const float* __restrict__ owT, const float* __restrict__ out_b,
        float* __restrict__ out) {
    int b = blockIdx.x >> 6;
    int n0 = (blockIdx.x & 63) * 4;
    int t = threadIdx.x;
    __shared__ __align__(16) float xl[4][INNER];
    for (int idx = t; idx < 4 * INNER; idx += 256) {
        xl[idx >> 9][idx & 511] = aoT[(b * NQ + n0) * INNER + idx];
    }
    __syncthreads();
    float bo = out_b[t];
    float a0 = bo, a1 = bo, a2 = bo, a3 = bo;
    #pragma unroll 2
    for (int c4 = 0; c4 < 128; ++c4) {
        int c = c4 * 4;
        float w0 = owT[(c + 0) * DIMC + t];
        float w1 = owT[(c + 1) * DIMC + t];
        float w2 = owT[(c + 2) * DIMC + t];
        float w3 = owT[(c + 3) * DIMC + t];
        float4 x0 = *(const float4*)&xl[0][c];
        float4 x1 = *(const float4*)&xl[1][c];
        float4 x2 = *(const float4*)&xl[2][c];
        float4 x3 = *(const float4*)&xl[3][c];
        a0 = fmaf(w0, x0.x, a0); a0 = fmaf(w1, x0.y, a0); a0 = fmaf(w2, x0.z, a0); a0 = fmaf(w3, x0.w, a0);
        a1 = fmaf(w0, x1.x, a1); a1 = fmaf(w1, x1.y, a1); a1 = fmaf(w2, x1.z, a1); a1 = fmaf(w3, x1.w, a1);
        a2 = fmaf(w0, x2.x, a2); a2 = fmaf(w1, x2.y, a2); a2 = fmaf(w2, x2.z, a2); a2 = fmaf(w3, x2.w, a2);
        a3 = fmaf(w0, x3.x, a3); a3 = fmaf(w1, x3.y, a3); a3 = fmaf(w2, x3.z, a3); a3 = fmaf(w3, x3.w, a3);
    }
    float4 res; res.x = a0; res.y = a1; res.z = a2; res.w = a3;
    *(float4*)(out + (b * DIMC + t) * NQ + n0) = res;
}

extern "C" void kernel_launch(void* const* d_in, const int* in_sizes, int n_in,
                              void* d_out, int out_size, void* d_ws, size_t ws_size,
                              hipStream_t stream) {
    const float* pose_feat = (const float*)d_in[0];
    const float* rgb       = (const float*)d_in[1];
    const float* pose_init = (const float*)d_in[2];
    const float* mha_in_w  = (const float*)d_in[3];
    const float* mha_in_b  = (const float*)d_in[4];
    const float* mha_out_w = (const float*)d_in[5];
    const float* mha_out_b = (const float*)d_in[6];
    const float* pe_gauss  = (const float*)d_in[7];
    const float* off_w1    = (const float*)d_in[8];
    const float* off_b1    = (const float*)d_in[9];
    const float* off_w2    = (const float*)d_in[10];
    const float* cpb_w0    = (const float*)d_in[11];
    const float* cpb_b0    = (const float*)d_in[12];
    const float* cpb_w1    = (const float*)d_in[13];
    const float* cpb_b1    = (const float*)d_in[14];
    const float* cpb_w2    = (const float*)d_in[15];
    const float* cpb_b2    = (const float*)d_in[16];
    const float* q_w       = (const float*)d_in[17];
    const float* k_w       = (const float*)d_in[18];
    const float* v_w       = (const float*)d_in[19];
    const float* out_w     = (const float*)d_in[20];
    const float* out_b     = (const float*)d_in[21];

    float* ws    = (float*)d_ws;
    float* kx    = ws;                     // 16384
    float* vx    = kx + 16384;             // 16384
    float* qT    = vx + 16384;             // 524288
    float* kTt   = qT + 524288;            // 524288
    float* vT    = kTt + 524288;           // 524288
    float* vgrid = vT + 524288;            // 16384
    float* aoT   = vgrid + 16384;          // 524288
    float* WqT   = aoT + 524288;           // 65536
    float* mowT  = WqT + 65536;            // 65536
    float* owT   = mowT + 65536;           // 131072
    float* qwT   = owT + 131072;           // 16384
    float* kwT   = qwT + 16384;            // 16384
    float* vwT   = kwT + 16384;            // 16384
    ushort_t* bias = (ushort_t*)(vwT + 16384);   // 32*256*256 bf16 = 4 MB
    float* out   = (float*)d_out;

    k0_tr<<<1216, 256, 0, stream>>>(mha_in_w, mha_out_w, out_w, q_w, k_w, v_w,
        WqT, mowT, owT, qwT, kwT, vwT);
    k1_kv<<<64, 256, 0, stream>>>(rgb, mha_in_w, mha_in_b, kx, vx);
    k2_qkv<<<256, 256, 0, stream>>>(pose_feat, rgb, pose_init, mha_in_b,
        WqT, mowT, mha_out_b, pe_gauss, off_w1, off_b1, off_w2, qwT, kwT, vwT,
        kx, vx, qT, kTt, vT, vgrid);
    k3a_bias<<<2048, 256, 0, stream>>>(pose_init, vgrid,
        cpb_w0, cpb_b0, cpb_w1, cpb_b1, cpb_w2, cpb_b2, bias);
    k3b_attn<<<1024, 256, 0, stream>>>(qT, kTt, vT, bias, aoT);
    k4_proj<<<256, 256, 0, stream>>>(aoT, owT, out_b, out);
}

// Round 9
// 187.287 us; speedup vs baseline: 1.6634x; 1.0150x over previous
//
#include <hip/hip_runtime.h>
#include <hip/hip_bf16.h>
#include <math.h>

// DeformableAttention2D — round 9: k3a swapped-operand MFMA (A=w1, B=h0) so
// the layer-2 reduce is 2 shfl instead of 16; grid 2048->4096. Rest unchanged.
// Sizes (fixed): B=4, N=256, DIM=256, HEADS=8, GROUPS=8, INNER=512, DH=64,
// cross-attn head dim 32, rgb 4x4 (16 tokens), CPB MLP 2->64->64->1.

#define DIMC 256
#define NQ 256
#define HEADS 8
#define GROUPS 8
#define INNER 512
#define DH 64
#define HDX 32
#define HWT 16

typedef __attribute__((ext_vector_type(8))) short short8v;
typedef __attribute__((ext_vector_type(4))) float f32x4;
typedef unsigned short ushort_t;

__device__ __forceinline__ float gelu_exact(float x) {
    return 0.5f * x * (1.f + erff(x * 0.70710678118654752f));
}
__device__ __forceinline__ short f2bf(float x) {
    union { float f; unsigned u; } c; c.f = x;
    unsigned r = c.u + 0x7fffu + ((c.u >> 16) & 1u);
    return (short)(r >> 16);
}
__device__ __forceinline__ short f2bf_hw(float x) {   // HW cvt (packs to v_cvt_pk_bf16_f32)
    return (short)__bfloat16_as_ushort(__float2bfloat16(x));
}
__device__ __forceinline__ float bf2f(unsigned hbits) {
    union { unsigned u; float f; } c; c.u = hbits << 16;
    return c.f;
}
__device__ __forceinline__ float samp4(const float* __restrict__ img, int yi, int xi) {
    bool valid = (xi >= 0) && (xi < 4) && (yi >= 0) && (yi < 4);
    int idx = min(max(yi, 0), 3) * 4 + min(max(xi, 0), 3);
    return valid ? img[idx] : 0.f;
}

// ---------------- K0: weight transposes ----------------
__global__ __launch_bounds__(256) void k0_tr(
        const float* __restrict__ in_w, const float* __restrict__ mow,
        const float* __restrict__ out_w, const float* __restrict__ q_w,
        const float* __restrict__ k_w, const float* __restrict__ v_w,
        float* __restrict__ WqT, float* __restrict__ mowT,
        float* __restrict__ owT, float* __restrict__ qwT,
        float* __restrict__ kwT, float* __restrict__ vwT) {
    int idx = blockIdx.x * 256 + threadIdx.x;
    if (idx < 65536) {
        int d = idx >> 8, o = idx & 255;
        WqT[idx] = in_w[o * 256 + d];
    } else if (idx < 131072) {
        int k = idx - 65536; int d = k >> 8, o = k & 255;
        mowT[k] = mow[o * 256 + d];
    } else if (idx < 262144) {
        int k = idx - 131072; int c = k >> 8, o = k & 255;
        owT[k] = out_w[o * 512 + c];
    } else if (idx < 278528) {
        int k = idx - 262144; int ci = k >> 9, ch = k & 511;
        qwT[k] = q_w[ch * 32 + ci];
    } else if (idx < 294912) {
        int k = idx - 278528; int ci = k >> 9, ch = k & 511;
        kwT[k] = k_w[ch * 32 + ci];
    } else if (idx < 311296) {
        int k = idx - 294912; int ci = k >> 9, ch = k & 511;
        vwT[k] = v_w[ch * 32 + ci];
    }
}

// ---------------- K1: kx, vx  [b,16,256] ----------------
__global__ __launch_bounds__(256) void k1_kv(const float* __restrict__ rgb,
        const float* __restrict__ in_w, const float* __restrict__ in_b,
        float* __restrict__ kx, float* __restrict__ vx) {
    int b = blockIdx.x >> 4;
    int tt = blockIdx.x & 15;
    int c = threadIdx.x;
    __shared__ __align__(16) float kvin[DIMC];
    float ang = (float)tt * powf(10000.f, -(float)(c >> 1) * (1.f / 128.f));
    float sv = (c & 1) ? cosf(ang) : sinf(ang);
    kvin[c] = rgb[(b * DIMC + c) * HWT + tt] + sv;
    __syncthreads();
    const float4* x4 = (const float4*)kvin;
    const float4* wk4 = (const float4*)(in_w + (DIMC + c) * DIMC);
    const float4* wv4 = (const float4*)(in_w + (2 * DIMC + c) * DIMC);
    float ak0 = in_b[DIMC + c], ak1 = 0.f, av0 = in_b[2 * DIMC + c], av1 = 0.f;
    #pragma unroll 4
    for (int d4 = 0; d4 < 64; ++d4) {
        float4 x = x4[d4], wk = wk4[d4], wv = wv4[d4];
        ak0 = fmaf(wk.x, x.x, ak0); ak1 = fmaf(wk.y, x.y, ak1);
        ak0 = fmaf(wk.z, x.z, ak0); ak1 = fmaf(wk.w, x.w, ak1);
        av0 = fmaf(wv.x, x.x, av0); av1 = fmaf(wv.y, x.y, av1);
        av0 = fmaf(wv.z, x.z, av0); av1 = fmaf(wv.w, x.w, av1);
    }
    kx[(b * HWT + tt) * DIMC + c] = ak0 + ak1;
    vx[(b * HWT + tt) * DIMC + c] = av0 + av1;
}

// ---------------- K2: 4 rows per block ----------------
__global__ __launch_bounds__(256) void k2_qkv(
        const float* __restrict__ pose_feat, const float* __restrict__ rgb,
        const float* __restrict__ pose_init, const float* __restrict__ in_b,
        const float* __restrict__ WqT, const float* __restrict__ mowT,
        const float* __restrict__ mob, const float* __restrict__ pe_gauss,
        const float* __restrict__ off_w1, const float* __restrict__ off_b1,
        const float* __restrict__ off_w2,
        const float* __restrict__ qwT, const float* __restrict__ kwT,
        const float* __restrict__ vwT,
        const float* __restrict__ kx, const float* __restrict__ vx,
        float* __restrict__ qT, float* __restrict__ kTt, float* __restrict__ vT,
        float* __restrict__ vgrid_g) {
    int b = blockIdx.x >> 6;
    int n0 = (blockIdx.x & 63) * 4;
    int t = threadIdx.x;
    __shared__ __align__(16) float xs[4][DIMC];
    __shared__ __align__(16) float qxs[4][DIMC];
    __shared__ __align__(16) float ctx[4][DIMC];
    __shared__ __align__(16) float x2[4][DIMC];
    __shared__ float lg[4][128], psm[4][128];
    __shared__ float qls[4][INNER];
    __shared__ float kvs[4][DIMC];
    __shared__ float vg[4][GROUPS][2];
    __shared__ float g01[4][2];

    if (t < 8) {
        int r = t >> 1, comp = t & 1;
        g01[r][comp] = 2.f * pose_init[(b * 2 + comp) * NQ + n0 + r] - 1.f;
    }
    float4 pf4 = *(const float4*)(pose_feat + (b * DIMC + t) * NQ + n0);
    float pfv[4] = {pf4.x, pf4.y, pf4.z, pf4.w};
    __syncthreads();
    {
        int j = t & 127;
        float pj0 = pe_gauss[j], pj1 = pe_gauss[128 + j];
        #pragma unroll
        for (int r = 0; r < 4; ++r) {
            float cc = (g01[r][0] * pj0 + g01[r][1] * pj1) * 6.28318530717958648f;
            float sc = (t < 128) ? sinf(cc) : cosf(cc);
            xs[r][t] = pfv[r] + sc;
        }
    }
    __syncthreads();
    {
        float bq = in_b[t];
        float a0 = bq, a1 = bq, a2 = bq, a3 = bq;
        #pragma unroll 2
        for (int d4 = 0; d4 < 64; ++d4) {
            int d = d4 * 4;
            float w0 = WqT[(d + 0) * DIMC + t];
            float w1 = WqT[(d + 1) * DIMC + t];
            float w2 = WqT[(d + 2) * DIMC + t];
            float w3 = WqT[(d + 3) * DIMC + t];
            float4 x0 = *(const float4*)&xs[0][d];
            float4 x1 = *(const float4*)&xs[1][d];
            float4 x2_ = *(const float4*)&xs[2][d];
            float4 x3 = *(const float4*)&xs[3][d];
            a0 = fmaf(w0, x0.x, a0); a0 = fmaf(w1, x0.y, a0); a0 = fmaf(w2, x0.z, a0); a0 = fmaf(w3, x0.w, a0);
            a1 = fmaf(w0, x1.x, a1); a1 = fmaf(w1, x1.y, a1); a1 = fmaf(w2, x1.z, a1); a1 = fmaf(w3, x1.w, a1);
            a2 = fmaf(w0, x2_.x, a2); a2 = fmaf(w1, x2_.y, a2); a2 = fmaf(w2, x2_.z, a2); a2 = fmaf(w3, x2_.w, a2);
            a3 = fmaf(w0, x3.x, a3); a3 = fmaf(w1, x3.y, a3); a3 = fmaf(w2, x3.z, a3); a3 = fmaf(w3, x3.w, a3);
        }
        qxs[0][t] = a0; qxs[1][t] = a1; qxs[2][t] = a2; qxs[3][t] = a3;
    }
    __syncthreads();
    #pragma unroll
    for (int rep = 0; rep < 2; ++rep) {
        int idx = rep * 256 + t;
        int r = idx >> 7, hh = (idx >> 4) & 7, tt = idx & 15;
        const float4* kp = (const float4*)(kx + (b * HWT + tt) * DIMC + hh * HDX);
        const float4* qp = (const float4*)(&qxs[r][hh * HDX]);
        float a = 0.f;
        #pragma unroll
        for (int d4 = 0; d4 < 8; ++d4) {
            float4 k4 = kp[d4], q4 = qp[d4];
            a = fmaf(q4.x, k4.x, a); a = fmaf(q4.y, k4.y, a);
            a = fmaf(q4.z, k4.z, a); a = fmaf(q4.w, k4.w, a);
        }
        lg[r][hh * 16 + tt] = a * 0.17677669529663689f;
    }
    __syncthreads();
    if (t < 32) {
        int r = t >> 3, hh = t & 7;
        float m = -1e30f;
        for (int tt = 0; tt < 16; ++tt) m = fmaxf(m, lg[r][hh * 16 + tt]);
        float s = 0.f;
        for (int tt = 0; tt < 16; ++tt) {
            float e = __expf(lg[r][hh * 16 + tt] - m);
            psm[r][hh * 16 + tt] = e; s += e;
        }
        float rr = 1.f / s;
        for (int tt = 0; tt < 16; ++tt) psm[r][hh * 16 + tt] *= rr;
    }
    __syncthreads();
    {
        int hh = t >> 5;
        const float* vp = vx + b * HWT * DIMC + t;
        float a0 = 0.f, a1 = 0.f, a2 = 0.f, a3 = 0.f;
        #pragma unroll
        for (int tt = 0; tt < 16; ++tt) {
            float vv = vp[tt * DIMC];
            a0 = fmaf(psm[0][hh * 16 + tt], vv, a0);
            a1 = fmaf(psm[1][hh * 16 + tt], vv, a1);
            a2 = fmaf(psm[2][hh * 16 + tt], vv, a2);
            a3 = fmaf(psm[3][hh * 16 + tt], vv, a3);
        }
        ctx[0][t] = a0; ctx[1][t] = a1; ctx[2][t] = a2; ctx[3][t] = a3;
    }
    __syncthreads();
    {
        float bm = mob[t];
        float a0 = bm, a1 = bm, a2 = bm, a3 = bm;
        #pragma unroll 2
        for (int d4 = 0; d4 < 64; ++d4) {
            int d = d4 * 4;
            float w0 = mowT[(d + 0) * DIMC + t];
            float w1 = mowT[(d + 1) * DIMC + t];
            float w2 = mowT[(d + 2) * DIMC + t];
            float w3 = mowT[(d + 3) * DIMC + t];
            float4 c0 = *(const float4*)&ctx[0][d];
            float4 c1 = *(const float4*)&ctx[1][d];
            float4 c2 = *(const float4*)&ctx[2][d];
            float4 c3 = *(const float4*)&ctx[3][d];
            a0 = fmaf(w0, c0.x, a0); a0 = fmaf(w1, c0.y, a0); a0 = fmaf(w2, c0.z, a0); a0 = fmaf(w3, c0.w, a0);
            a1 = fmaf(w0, c1.x, a1); a1 = fmaf(w1, c1.y, a1); a1 = fmaf(w2, c1.z, a1); a1 = fmaf(w3, c1.w, a1);
            a2 = fmaf(w0, c2.x, a2); a2 = fmaf(w1, c2.y, a2); a2 = fmaf(w2, c2.z, a2); a2 = fmaf(w3, c2.w, a2);
            a3 = fmaf(w0, c3.x, a3); a3 = fmaf(w1, c3.y, a3); a3 = fmaf(w2, c3.z, a3); a3 = fmaf(w3, c3.w, a3);
        }
        x2[0][t] = pfv[0] + a0; x2[1][t] = pfv[1] + a1;
        x2[2][t] = pfv[2] + a2; x2[3][t] = pfv[3] + a3;
    }
    __syncthreads();
    #pragma unroll
    for (int rep = 0; rep < 2; ++rep) {
        int ch = rep * 256 + t;
        int g = ch >> 6;
        float aq[4] = {0.f, 0.f, 0.f, 0.f};
        #pragma unroll
        for (int ci = 0; ci < 32; ++ci) {
            float w = qwT[ci * INNER + ch];
            aq[0] = fmaf(w, x2[0][g * 32 + ci], aq[0]);
            aq[1] = fmaf(w, x2[1][g * 32 + ci], aq[1]);
            aq[2] = fmaf(w, x2[2][g * 32 + ci], aq[2]);
            aq[3] = fmaf(w, x2[3][g * 32 + ci], aq[3]);
        }
        #pragma unroll
        for (int r = 0; r < 4; ++r) {
            qls[r][ch] = aq[r];
            qT[(b * NQ + n0 + r) * INNER + ch] = aq[r];
        }
    }
    __syncthreads();
    {
        int pr = t >> 3, l = t & 7;
        int r = pr >> 3, g = pr & 7;
        float s0 = 0.f, s1 = 0.f;
        #pragma unroll
        for (int e = 0; e < 8; ++e) {
            int jj = l * 8 + e;
            float ev = gelu_exact(fmaf(qls[r][g * 64 + jj], off_w1[jj], off_b1[jj]));
            s0 = fmaf(ev, off_w2[jj], s0);
            s1 = fmaf(ev, off_w2[64 + jj], s1);
        }
        #pragma unroll
        for (int o = 4; o > 0; o >>= 1) {
            s0 += __shfl_xor(s0, o, 64);
            s1 += __shfl_xor(s1, o, 64);
        }
        if (l == 0) {
            float vgx = g01[r][0] + tanhf(s0) * (2.f / 3.f);
            float vgy = g01[r][1] + tanhf(s1) * (2.f / 3.f);
            vg[r][g][0] = vgx; vg[r][g][1] = vgy;
            float* vp = vgrid_g + ((b * GROUPS + g) * NQ + n0 + r) * 2;
            vp[0] = vgx; vp[1] = vgy;
        }
    }
    __syncthreads();
    #pragma unroll
    for (int rep = 0; rep < 4; ++rep) {
        int idx = rep * 256 + t;
        int r = idx >> 8, c = idx & 255, g = c >> 5;
        float x = (vg[r][g][0] + 1.f) * 2.f - 0.5f;
        float y = (vg[r][g][1] + 1.f) * 2.f - 0.5f;
        float x0f = floorf(x), y0f = floorf(y);
        float wx = x - x0f, wy = y - y0f;
        int x0 = (int)x0f, y0 = (int)y0f;
        const float* img = rgb + (b * DIMC + c) * HWT;
        float v00 = samp4(img, y0, x0), v01 = samp4(img, y0, x0 + 1);
        float v10 = samp4(img, y0 + 1, x0), v11 = samp4(img, y0 + 1, x0 + 1);
        kvs[r][c] = v00 * (1.f - wx) * (1.f - wy) + v01 * wx * (1.f - wy)
                  + v10 * (1.f - wx) * wy + v11 * wx * wy;
    }
    __syncthreads();
    // grouped k/v convs; K transposed [bg][d][n], V row-major [b][n][inner]
    #pragma unroll
    for (int rep = 0; rep < 2; ++rep) {
        int ch = rep * 256 + t;
        int g = ch >> 6;
        float ak[4] = {0.f, 0.f, 0.f, 0.f};
        float av[4] = {0.f, 0.f, 0.f, 0.f};
        #pragma unroll
        for (int ci = 0; ci < 32; ++ci) {
            float wk = kwT[ci * INNER + ch];
            float wv = vwT[ci * INNER + ch];
            #pragma unroll
            for (int r = 0; r < 4; ++r) {
                float x = kvs[r][g * 32 + ci];
                ak[r] = fmaf(wk, x, ak[r]);
                av[r] = fmaf(wv, x, av[r]);
            }
        }
        int hh = ch >> 6, dh = ch & 63;
        float4 kk; kk.x = ak[0]; kk.y = ak[1]; kk.z = ak[2]; kk.w = ak[3];
        *(float4*)(kTt + ((b * HEADS + hh) * DH + dh) * NQ + n0) = kk;
        #pragma unroll
        for (int r = 0; r < 4; ++r)
            vT[(b * NQ + n0 + r) * INNER + ch] = av[r];
    }
}

// ---------------- K3a: CPB bias via MFMA, swapped operands ----------------
// grid 4096: blockIdx = ((bg*16 + jt)*8 + itc); wave: 4 j, 2 i-tiles of 16.
// mfma(A=w1, B=h0): C col (lane&15) = output pair p (i = it*16+p),
// C row (4*lgp+reg) = c2. Layer-2 reduce: in-lane over (nt,reg) + 2 shfl
// over lgp. Both operands share the (lane,e)->k map, so the contraction is
// correct under any internal k-permutation.
__global__ __launch_bounds__(256) void k3a_bias(
        const float* __restrict__ pose_init, const float* __restrict__ vgrid_g,
        const float* __restrict__ w0, const float* __restrict__ b0,
        const float* __restrict__ w1, const float* __restrict__ b1,
        const float* __restrict__ w2, const float* __restrict__ b2,
        ushort_t* __restrict__ bias) {
    int bg = blockIdx.x >> 7;
    int jt = (blockIdx.x >> 3) & 15;
    int itc = blockIdx.x & 7;
    int b = bg >> 3;
    int tid = threadIdx.x;
    int wv = tid >> 6, lane = tid & 63;
    int lgp = lane >> 4, lr = lane & 15;

    __shared__ float gx_s[32], gy_s[32];
    if (tid < 32) {
        int i = itc * 32 + tid;
        gx_s[tid] = 2.f * pose_init[(b * 2 + 0) * NQ + i] - 1.f;
        gy_s[tid] = 2.f * pose_init[(b * 2 + 1) * NQ + i] - 1.f;
    }
    __syncthreads();

    // layer-0 weights for this lane's k-slice (k = kc*32 + lgp*8 + e)
    float w0a[2][8], w0b[2][8], b0r[2][8];
    #pragma unroll
    for (int kc = 0; kc < 2; ++kc)
        #pragma unroll
        for (int e = 0; e < 8; ++e) {
            int c = kc * 32 + lgp * 8 + e;
            w0a[kc][e] = w0[2 * c];
            w0b[kc][e] = w0[2 * c + 1];
            b0r[kc][e] = b0[c];
        }
    // w1 as A-fragment: row c2 = nt*16 + lr, k = kc*32 + lgp*8 + e
    short8v bw1[2][4];
    #pragma unroll
    for (int nt = 0; nt < 4; ++nt) {
        int c2 = nt * 16 + lr;
        #pragma unroll
        for (int kc = 0; kc < 2; ++kc)
            #pragma unroll
            for (int e = 0; e < 8; ++e)
                bw1[kc][nt][e] = f2bf(w1[c2 * 64 + kc * 32 + lgp * 8 + e]);
    }
    // b1/w2 for this lane's C rows: c2 = nt*16 + 4*lgp + r
    f32x4 b1v[4], w2v[4];
    #pragma unroll
    for (int nt = 0; nt < 4; ++nt) {
        b1v[nt] = *(const f32x4*)&b1[nt * 16 + 4 * lgp];
        w2v[nt] = *(const f32x4*)&w2[nt * 16 + 4 * lgp];
    }
    float b2v = b2[0];

    int j0 = jt * 16 + wv * 4;
    const float* vgp = vgrid_g + bg * NQ * 2;
    float vgxr[4], vgyr[4];
    #pragma unroll
    for (int jj = 0; jj < 4; ++jj) {
        vgxr[jj] = vgp[(j0 + jj) * 2];
        vgyr[jj] = vgp[(j0 + jj) * 2 + 1];
    }

    #pragma unroll 1
    for (int it2 = 0; it2 < 2; ++it2) {
        int it = itc * 2 + it2;
        float gxi = gx_s[it2 * 16 + lr], gyi = gy_s[it2 * 16 + lr];
        #pragma unroll 2
        for (int jj = 0; jj < 4; ++jj) {
            int j = j0 + jj;
            float px = gxi - vgxr[jj], py = gyi - vgyr[jj];
            float u = copysignf(__logf(1.f + fabsf(px)), px);
            float vvl = copysignf(__logf(1.f + fabsf(py)), py);
            // B-fragment: h0 for col p = lr, k-slices per lgp
            short8v hb0, hb1;
            #pragma unroll
            for (int e = 0; e < 8; ++e) {
                float h = fmaf(w0a[0][e], u, fmaf(w0b[0][e], vvl, b0r[0][e]));
                hb0[e] = f2bf_hw(fmaxf(h, 0.f));
            }
            #pragma unroll
            for (int e = 0; e < 8; ++e) {
                float h = fmaf(w0a[1][e], u, fmaf(w0b[1][e], vvl, b0r[1][e]));
                hb1[e] = f2bf_hw(fmaxf(h, 0.f));
            }
            f32x4 acc0 = {0.f, 0.f, 0.f, 0.f};
            f32x4 acc1 = {0.f, 0.f, 0.f, 0.f};
            f32x4 acc2 = {0.f, 0.f, 0.f, 0.f};
            f32x4 acc3 = {0.f, 0.f, 0.f, 0.f};
            acc0 = __builtin_amdgcn_mfma_f32_16x16x32_bf16(bw1[0][0], hb0, acc0, 0, 0, 0);
            acc0 = __builtin_amdgcn_mfma_f32_16x16x32_bf16(bw1[1][0], hb1, acc0, 0, 0, 0);
            acc1 = __builtin_amdgcn_mfma_f32_16x16x32_bf16(bw1[0][1], hb0, acc1, 0, 0, 0);
            acc1 = __builtin_amdgcn_mfma_f32_16x16x32_bf16(bw1[1][1], hb1, acc1, 0, 0, 0);
            acc2 = __builtin_amdgcn_mfma_f32_16x16x32_bf16(bw1[0][2], hb0, acc2, 0, 0, 0);
            acc2 = __builtin_amdgcn_mfma_f32_16x16x32_bf16(bw1[1][2], hb1, acc2, 0, 0, 0);
            acc3 = __builtin_amdgcn_mfma_f32_16x16x32_bf16(bw1[0][3], hb0, acc3, 0, 0, 0);
            acc3 = __builtin_amdgcn_mfma_f32_16x16x32_bf16(bw1[1][3], hb1, acc3, 0, 0, 0);
            // layer-2: in-lane partial over (nt, r), then 4-way lgp reduce
            float s = 0.f;
            #pragma unroll
            for (int r = 0; r < 4; ++r) {
                s += fmaxf(acc0[r] + b1v[0][r], 0.f) * w2v[0][r];
                s += fmaxf(acc1[r] + b1v[1][r], 0.f) * w2v[1][r];
                s += fmaxf(acc2[r] + b1v[2][r], 0.f) * w2v[2][r];
                s += fmaxf(acc3[r] + b1v[3][r], 0.f) * w2v[3][r];
            }
            s += __shfl_xor(s, 16, 64);
            s += __shfl_xor(s, 32, 64);
            if (lane < 16)
                bias[(bg * NQ + it * 16 + lr) * NQ + j] = (ushort_t)f2bf(s + b2v);
        }
    }
}

// ---------------- K3b: sim + bias + softmax + attn@V ----------------
__global__ __launch_bounds__(256) void k3b_attn(
        const float* __restrict__ qT, const float* __restrict__ kTt,
        const float* __restrict__ vT, const ushort_t* __restrict__ bias,
        float* __restrict__ aoT) {
    int bg = blockIdx.x >> 5;
    int itile = blockIdx.x & 31;
    int b = bg >> 3, h = bg & 7;
    int i0 = itile * 8;
    int tid = threadIdx.x;

    __shared__ __align__(16) float q_s[8][64];
    __shared__ __align__(16) float attn_s[8][NQ];
    __shared__ float ssum_s[8];

    for (int idx = tid; idx < 8 * 64; idx += 256) {
        int i = idx >> 6, d = idx & 63;
        q_s[i][d] = qT[(b * NQ + i0 + i) * INNER + h * 64 + d] * 0.125f;
    }
    __syncthreads();

    {
        int jq = tid & 63, ih = tid >> 6;
        const float4* kb4 = (const float4*)(kTt + bg * DH * NQ) + jq;
        float4 s0 = {0.f, 0.f, 0.f, 0.f};
        float4 s1 = {0.f, 0.f, 0.f, 0.f};
        #pragma unroll 4
        for (int d = 0; d < 64; ++d) {
            float4 kv = kb4[d * 64];
            float q0 = q_s[ih][d], q1 = q_s[ih + 4][d];
            s0.x = fmaf(q0, kv.x, s0.x); s0.y = fmaf(q0, kv.y, s0.y);
            s0.z = fmaf(q0, kv.z, s0.z); s0.w = fmaf(q0, kv.w, s0.w);
            s1.x = fmaf(q1, kv.x, s1.x); s1.y = fmaf(q1, kv.y, s1.y);
            s1.z = fmaf(q1, kv.z, s1.z); s1.w = fmaf(q1, kv.w, s1.w);
        }
        uint2 bb0 = *(const uint2*)(bias + (bg * NQ + i0 + ih) * NQ + jq * 4);
        uint2 bb1 = *(const uint2*)(bias + (bg * NQ + i0 + ih + 4) * NQ + jq * 4);
        s0.x += bf2f(bb0.x & 0xffffu); s0.y += bf2f(bb0.x >> 16);
        s0.z += bf2f(bb0.y & 0xffffu); s0.w += bf2f(bb0.y >> 16);
        s1.x += bf2f(bb1.x & 0xffffu); s1.y += bf2f(bb1.x >> 16);
        s1.z += bf2f(bb1.y & 0xffffu); s1.w += bf2f(bb1.y >> 16);
        *(float4*)&attn_s[ih][jq * 4] = s0;
        *(float4*)&attn_s[ih + 4][jq * 4] = s1;
    }
    __syncthreads();
    {
        int il = tid >> 5, lane = tid & 31;
        float m = -1e30f;
        for (int jj = 0; jj < 8; ++jj) m = fmaxf(m, attn_s[il][jj * 32 + lane]);
        #pragma unroll
        for (int o = 16; o > 0; o >>= 1) m = fmaxf(m, __shfl_xor(m, o, 32));
        float s = 0.f;
        for (int jj = 0; jj < 8; ++jj) {
            int j = jj * 32 + lane;
            float e = __expf(attn_s[il][j] - m);
            attn_s[il][j] = e;
            s += e;
        }
        #pragma unroll
        for (int o = 16; o > 0; o >>= 1) s += __shfl_xor(s, o, 32);
        if (lane == 0) ssum_s[il] = s;
    }
    __syncthreads();
    {
        int lane = tid & 31, il = tid >> 5;
        const float2* vp = (const float2*)(vT + b * NQ * INNER + h * 64) + lane;
        float a0 = 0.f, a1 = 0.f, c0 = 0.f, c1 = 0.f;
        #pragma unroll 4
        for (int j = 0; j < NQ; j += 2) {
            float w0 = attn_s[il][j], w1 = attn_s[il][j + 1];
            float2 v0 = vp[j * (INNER / 2)];
            float2 v1 = vp[(j + 1) * (INNER / 2)];
            a0 = fmaf(w0, v0.x, a0); a1 = fmaf(w0, v0.y, a1);
            c0 = fmaf(w1, v1.x, c0); c1 = fmaf(w1, v1.y, c1);
        }
        float r = 1.f / ssum_s[il];
        float2 res; res.x = (a0 + c0) * r; res.y = (a1 + c1) * r;
        *(float2*)(aoT + (b * NQ + i0 + il) * INNER + h * 64 + lane * 2) = res;
    }
}

// ---------------- K4: final projection 512 -> 256 (coalesced owT) ----------------
__global__ __launch_bounds__(256) void k4_proj(const float* __restrict__ aoT,
        const float* __restrict__ owT, const float* __restrict__ out_b,
        float* __restrict__ out) {
    int b = blockIdx.x >> 6;
    int n0 = (blockIdx.x & 63) * 4;
    int t = threadIdx.x;
    __shared__ __align__(16) float xl[4][INNER];
    for (int idx = t; idx < 4 * INNER; idx += 256) {
        xl[idx >> 9][idx & 511] = aoT[(b * NQ + n0) * INNER + idx];
    }
    __syncthreads();
    float bo = out_b[t];
    float a0 = bo, a1 = bo, a2 = bo, a3 = bo;
    #pragma unroll 2
    for (int c4 = 0; c4 < 128; ++c4) {
        int c = c4 * 4;
        float w0 = owT[(c + 0) * DIMC + t];
        float w1 = owT[(c + 1) * DIMC + t];
        float w2 = owT[(c + 2) * DIMC + t];
        float w3 = owT[(c + 3) * DIMC + t];
        float4 x0 = *(const float4*)&xl[0][c];
        float4 x1 = *(const float4*)&xl[1][c];
        float4 x2 = *(const float4*)&xl[2][c];
        float4 x3 = *(const float4*)&xl[3][c];
        a0 = fmaf(w0, x0.x, a0); a0 = fmaf(w1, x0.y, a0); a0 = fmaf(w2, x0.z, a0); a0 = fmaf(w3, x0.w, a0);
        a1 = fmaf(w0, x1.x, a1); a1 = fmaf(w1, x1.y, a1); a1 = fmaf(w2, x1.z, a1); a1 = fmaf(w3, x1.w, a1);
        a2 = fmaf(w0, x2.x, a2); a2 = fmaf(w1, x2.y, a2); a2 = fmaf(w2, x2.z, a2); a2 = fmaf(w3, x2.w, a2);
        a3 = fmaf(w0, x3.x, a3); a3 = fmaf(w1, x3.y, a3); a3 = fmaf(w2, x3.z, a3); a3 = fmaf(w3, x3.w, a3);
    }
    float4 res; res.x = a0; res.y = a1; res.z = a2; res.w = a3;
    *(float4*)(out + (b * DIMC + t) * NQ + n0) = res;
}

extern "C" void kernel_launch(void* const* d_in, const int* in_sizes, int n_in,
                              void* d_out, int out_size, void* d_ws, size_t ws_size,
                              hipStream_t stream) {
    const float* pose_feat = (const float*)d_in[0];
    const float* rgb       = (const float*)d_in[1];
    const float* pose_init = (const float*)d_in[2];
    const float* mha_in_w  = (const float*)d_in[3];
    const float* mha_in_b  = (const float*)d_in[4];
    const float* mha_out_w = (const float*)d_in[5];
    const float* mha_out_b = (const float*)d_in[6];
    const float* pe_gauss  = (const float*)d_in[7];
    const float* off_w1    = (const float*)d_in[8];
    const float* off_b1    = (const float*)d_in[9];
    const float* off_w2    = (const float*)d_in[10];
    const float* cpb_w0    = (const float*)d_in[11];
    const float* cpb_b0    = (const float*)d_in[12];
    const float* cpb_w1    = (const float*)d_in[13];
    const float* cpb_b1    = (const float*)d_in[14];
    const float* cpb_w2    = (const float*)d_in[15];
    const float* cpb_b2    = (const float*)d_in[16];
    const float* q_w       = (const float*)d_in[17];
    const float* k_w       = (const float*)d_in[18];
    const float* v_w       = (const float*)d_in[19];
    const float* out_w     = (const float*)d_in[20];
    const float* out_b     = (const float*)d_in[21];

    float* ws    = (float*)d_ws;
    float* kx    = ws;                     // 16384
    float* vx    = kx + 16384;             // 16384
    float* qT    = vx + 16384;             // 524288
    float* kTt   = qT + 524288;            // 524288
    float* vT    = kTt + 524288;           // 524288
    float* vgrid = vT + 524288;            // 16384
    float* aoT   = vgrid + 16384;          // 524288
    float* WqT   = aoT + 524288;           // 65536
    float* mowT  = WqT + 65536;            // 65536
    float* owT   = mowT + 65536;           // 131072
    float* qwT   = owT + 131072;           // 16384
    float* kwT   = qwT + 16384;            // 16384
    float* vwT   = kwT + 16384;            // 16384
    ushort_t* bias = (ushort_t*)(vwT + 16384);   // 32*256*256 bf16 = 4 MB
    float* out   = (float*)d_out;

    k0_tr<<<1216, 256, 0, stream>>>(mha_in_w, mha_out_w, out_w, q_w, k_w, v_w,
        WqT, mowT, owT, qwT, kwT, vwT);
    k1_kv<<<64, 256, 0, stream>>>(rgb, mha_in_w, mha_in_b, kx, vx);
    k2_qkv<<<256, 256, 0, stream>>>(pose_feat, rgb, pose_init, mha_in_b,
        WqT, mowT, mha_out_b, pe_gauss, off_w1, off_b1, off_w2, qwT, kwT, vwT,
        kx, vx, qT, kTt, vT, vgrid);
    k3a_bias<<<4096, 256, 0, stream>>>(pose_init, vgrid,
        cpb_w0, cpb_b0, cpb_w1, cpb_b1, cpb_w2, cpb_b2, bias);
    k3b_attn<<<1024, 256, 0, stream>>>(qT, kTt, vT, bias, aoT);
    k4_proj<<<256, 256, 0, stream>>>(aoT, owT, out_b, out);
}

// Round 10
// 177.563 us; speedup vs baseline: 1.7545x; 1.0548x over previous
//
#include <hip/hip_runtime.h>
#include <hip/hip_bf16.h>
#include <math.h>

// DeformableAttention2D — round 10: k3a register-pressure fix. Evidence: r9
// VGPR_Count=92 but live state >=130 => compiler spills/remats ~40 regs per
// inner iteration (scratch/L2 latency dominates; explains flat r6->r9 perf).
// Fix: w0/b0 packed bf16 (48->24 regs), b1/w2 + vgrid tile in LDS, unroll 1.
// Sizes (fixed): B=4, N=256, DIM=256, HEADS=8, GROUPS=8, INNER=512, DH=64,
// cross-attn head dim 32, rgb 4x4 (16 tokens), CPB MLP 2->64->64->1.

#define DIMC 256
#define NQ 256
#define HEADS 8
#define GROUPS 8
#define INNER 512
#define DH 64
#define HDX 32
#define HWT 16

typedef __attribute__((ext_vector_type(8))) short short8v;
typedef __attribute__((ext_vector_type(4))) float f32x4;
typedef unsigned short ushort_t;

__device__ __forceinline__ float gelu_exact(float x) {
    return 0.5f * x * (1.f + erff(x * 0.70710678118654752f));
}
__device__ __forceinline__ short f2bf(float x) {
    union { float f; unsigned u; } c; c.f = x;
    unsigned r = c.u + 0x7fffu + ((c.u >> 16) & 1u);
    return (short)(r >> 16);
}
__device__ __forceinline__ short f2bf_hw(float x) {   // HW cvt (packs to v_cvt_pk_bf16_f32)
    return (short)__bfloat16_as_ushort(__float2bfloat16(x));
}
__device__ __forceinline__ float bf2f(unsigned hbits) {
    union { unsigned u; float f; } c; c.u = hbits << 16;
    return c.f;
}
__device__ __forceinline__ unsigned pack2bf(float lo, float hi) {
    return (unsigned)(ushort_t)f2bf(lo) | ((unsigned)(ushort_t)f2bf(hi) << 16);
}
__device__ __forceinline__ float samp4(const float* __restrict__ img, int yi, int xi) {
    bool valid = (xi >= 0) && (xi < 4) && (yi >= 0) && (yi < 4);
    int idx = min(max(yi, 0), 3) * 4 + min(max(xi, 0), 3);
    return valid ? img[idx] : 0.f;
}

// ---------------- K0: weight transposes ----------------
__global__ __launch_bounds__(256) void k0_tr(
        const float* __restrict__ in_w, const float* __restrict__ mow,
        const float* __restrict__ out_w, const float* __restrict__ q_w,
        const float* __restrict__ k_w, const float* __restrict__ v_w,
        float* __restrict__ WqT, float* __restrict__ mowT,
        float* __restrict__ owT, float* __restrict__ qwT,
        float* __restrict__ kwT, float* __restrict__ vwT) {
    int idx = blockIdx.x * 256 + threadIdx.x;
    if (idx < 65536) {
        int d = idx >> 8, o = idx & 255;
        WqT[idx] = in_w[o * 256 + d];
    } else if (idx < 131072) {
        int k = idx - 65536; int d = k >> 8, o = k & 255;
        mowT[k] = mow[o * 256 + d];
    } else if (idx < 262144) {
        int k = idx - 131072; int c = k >> 8, o = k & 255;
        owT[k] = out_w[o * 512 + c];
    } else if (idx < 278528) {
        int k = idx - 262144; int ci = k >> 9, ch = k & 511;
        qwT[k] = q_w[ch * 32 + ci];
    } else if (idx < 294912) {
        int k = idx - 278528; int ci = k >> 9, ch = k & 511;
        kwT[k] = k_w[ch * 32 + ci];
    } else if (idx < 311296) {
        int k = idx - 294912; int ci = k >> 9, ch = k & 511;
        vwT[k] = v_w[ch * 32 + ci];
    }
}

// ---------------- K1: kx, vx  [b,16,256] ----------------
__global__ __launch_bounds__(256) void k1_kv(const float* __restrict__ rgb,
        const float* __restrict__ in_w, const float* __restrict__ in_b,
        float* __restrict__ kx, float* __restrict__ vx) {
    int b = blockIdx.x >> 4;
    int tt = blockIdx.x & 15;
    int c = threadIdx.x;
    __shared__ __align__(16) float kvin[DIMC];
    float ang = (float)tt * powf(10000.f, -(float)(c >> 1) * (1.f / 128.f));
    float sv = (c & 1) ? cosf(ang) : sinf(ang);
    kvin[c] = rgb[(b * DIMC + c) * HWT + tt] + sv;
    __syncthreads();
    const float4* x4 = (const float4*)kvin;
    const float4* wk4 = (const float4*)(in_w + (DIMC + c) * DIMC);
    const float4* wv4 = (const float4*)(in_w + (2 * DIMC + c) * DIMC);
    float ak0 = in_b[DIMC + c], ak1 = 0.f, av0 = in_b[2 * DIMC + c], av1 = 0.f;
    #pragma unroll 4
    for (int d4 = 0; d4 < 64; ++d4) {
        float4 x = x4[d4], wk = wk4[d4], wv = wv4[d4];
        ak0 = fmaf(wk.x, x.x, ak0); ak1 = fmaf(wk.y, x.y, ak1);
        ak0 = fmaf(wk.z, x.z, ak0); ak1 = fmaf(wk.w, x.w, ak1);
        av0 = fmaf(wv.x, x.x, av0); av1 = fmaf(wv.y, x.y, av1);
        av0 = fmaf(wv.z, x.z, av0); av1 = fmaf(wv.w, x.w, av1);
    }
    kx[(b * HWT + tt) * DIMC + c] = ak0 + ak1;
    vx[(b * HWT + tt) * DIMC + c] = av0 + av1;
}

// ---------------- K2: 4 rows per block ----------------
__global__ __launch_bounds__(256) void k2_qkv(
        const float* __restrict__ pose_feat, const float* __restrict__ rgb,
        const float* __restrict__ pose_init, const float* __restrict__ in_b,
        const float* __restrict__ WqT, const float* __restrict__ mowT,
        const float* __restrict__ mob, const float* __restrict__ pe_gauss,
        const float* __restrict__ off_w1, const float* __restrict__ off_b1,
        const float* __restrict__ off_w2,
        const float* __restrict__ qwT, const float* __restrict__ kwT,
        const float* __restrict__ vwT,
        const float* __restrict__ kx, const float* __restrict__ vx,
        float* __restrict__ qT, float* __restrict__ kTt, float* __restrict__ vT,
        float* __restrict__ vgrid_g) {
    int b = blockIdx.x >> 6;
    int n0 = (blockIdx.x & 63) * 4;
    int t = threadIdx.x;
    __shared__ __align__(16) float xs[4][DIMC];
    __shared__ __align__(16) float qxs[4][DIMC];
    __shared__ __align__(16) float ctx[4][DIMC];
    __shared__ __align__(16) float x2[4][DIMC];
    __shared__ float lg[4][128], psm[4][128];
    __shared__ float qls[4][INNER];
    __shared__ float kvs[4][DIMC];
    __shared__ float vg[4][GROUPS][2];
    __shared__ float g01[4][2];

    if (t < 8) {
        int r = t >> 1, comp = t & 1;
        g01[r][comp] = 2.f * pose_init[(b * 2 + comp) * NQ + n0 + r] - 1.f;
    }
    float4 pf4 = *(const float4*)(pose_feat + (b * DIMC + t) * NQ + n0);
    float pfv[4] = {pf4.x, pf4.y, pf4.z, pf4.w};
    __syncthreads();
    {
        int j = t & 127;
        float pj0 = pe_gauss[j], pj1 = pe_gauss[128 + j];
        #pragma unroll
        for (int r = 0; r < 4; ++r) {
            float cc = (g01[r][0] * pj0 + g01[r][1] * pj1) * 6.28318530717958648f;
            float sc = (t < 128) ? sinf(cc) : cosf(cc);
            xs[r][t] = pfv[r] + sc;
        }
    }
    __syncthreads();
    {
        float bq = in_b[t];
        float a0 = bq, a1 = bq, a2 = bq, a3 = bq;
        #pragma unroll 2
        for (int d4 = 0; d4 < 64; ++d4) {
            int d = d4 * 4;
            float w0 = WqT[(d + 0) * DIMC + t];
            float w1 = WqT[(d + 1) * DIMC + t];
            float w2 = WqT[(d + 2) * DIMC + t];
            float w3 = WqT[(d + 3) * DIMC + t];
            float4 x0 = *(const float4*)&xs[0][d];
            float4 x1 = *(const float4*)&xs[1][d];
            float4 x2_ = *(const float4*)&xs[2][d];
            float4 x3 = *(const float4*)&xs[3][d];
            a0 = fmaf(w0, x0.x, a0); a0 = fmaf(w1, x0.y, a0); a0 = fmaf(w2, x0.z, a0); a0 = fmaf(w3, x0.w, a0);
            a1 = fmaf(w0, x1.x, a1); a1 = fmaf(w1, x1.y, a1); a1 = fmaf(w2, x1.z, a1); a1 = fmaf(w3, x1.w, a1);
            a2 = fmaf(w0, x2_.x, a2); a2 = fmaf(w1, x2_.y, a2); a2 = fmaf(w2, x2_.z, a2); a2 = fmaf(w3, x2_.w, a2);
            a3 = fmaf(w0, x3.x, a3); a3 = fmaf(w1, x3.y, a3); a3 = fmaf(w2, x3.z, a3); a3 = fmaf(w3, x3.w, a3);
        }
        qxs[0][t] = a0; qxs[1][t] = a1; qxs[2][t] = a2; qxs[3][t] = a3;
    }
    __syncthreads();
    #pragma unroll
    for (int rep = 0; rep < 2; ++rep) {
        int idx = rep * 256 + t;
        int r = idx >> 7, hh = (idx >> 4) & 7, tt = idx & 15;
        const float4* kp = (const float4*)(kx + (b * HWT + tt) * DIMC + hh * HDX);
        const float4* qp = (const float4*)(&qxs[r][hh * HDX]);
        float a = 0.f;
        #pragma unroll
        for (int d4 = 0; d4 < 8; ++d4) {
            float4 k4 = kp[d4], q4 = qp[d4];
            a = fmaf(q4.x, k4.x, a); a = fmaf(q4.y, k4.y, a);
            a = fmaf(q4.z, k4.z, a); a = fmaf(q4.w, k4.w, a);
        }
        lg[r][hh * 16 + tt] = a * 0.17677669529663689f;
    }
    __syncthreads();
    if (t < 32) {
        int r = t >> 3, hh = t & 7;
        float m = -1e30f;
        for (int tt = 0; tt < 16; ++tt) m = fmaxf(m, lg[r][hh * 16 + tt]);
        float s = 0.f;
        for (int tt = 0; tt < 16; ++tt) {
            float e = __expf(lg[r][hh * 16 + tt] - m);
            psm[r][hh * 16 + tt] = e; s += e;
        }
        float rr = 1.f / s;
        for (int tt = 0; tt < 16; ++tt) psm[r][hh * 16 + tt] *= rr;
    }
    __syncthreads();
    {
        int hh = t >> 5;
        const float* vp = vx + b * HWT * DIMC + t;
        float a0 = 0.f, a1 = 0.f, a2 = 0.f, a3 = 0.f;
        #pragma unroll
        for (int tt = 0; tt < 16; ++tt) {
            float vv = vp[tt * DIMC];
            a0 = fmaf(psm[0][hh * 16 + tt], vv, a0);
            a1 = fmaf(psm[1][hh * 16 + tt], vv, a1);
            a2 = fmaf(psm[2][hh * 16 + tt], vv, a2);
            a3 = fmaf(psm[3][hh * 16 + tt], vv, a3);
        }
        ctx[0][t] = a0; ctx[1][t] = a1; ctx[2][t] = a2; ctx[3][t] = a3;
    }
    __syncthreads();
    {
        float bm = mob[t];
        float a0 = bm, a1 = bm, a2 = bm, a3 = bm;
        #pragma unroll 2
        for (int d4 = 0; d4 < 64; ++d4) {
            int d = d4 * 4;
            float w0 = mowT[(d + 0) * DIMC + t];
            float w1 = mowT[(d + 1) * DIMC + t];
            float w2 = mowT[(d + 2) * DIMC + t];
            float w3 = mowT[(d + 3) * DIMC + t];
            float4 c0 = *(const float4*)&ctx[0][d];
            float4 c1 = *(const float4*)&ctx[1][d];
            float4 c2 = *(const float4*)&ctx[2][d];
            float4 c3 = *(const float4*)&ctx[3][d];
            a0 = fmaf(w0, c0.x, a0); a0 = fmaf(w1, c0.y, a0); a0 = fmaf(w2, c0.z, a0); a0 = fmaf(w3, c0.w, a0);
            a1 = fmaf(w0, c1.x, a1); a1 = fmaf(w1, c1.y, a1); a1 = fmaf(w2, c1.z, a1); a1 = fmaf(w3, c1.w, a1);
            a2 = fmaf(w0, c2.x, a2); a2 = fmaf(w1, c2.y, a2); a2 = fmaf(w2, c2.z, a2); a2 = fmaf(w3, c2.w, a2);
            a3 = fmaf(w0, c3.x, a3); a3 = fmaf(w1, c3.y, a3); a3 = fmaf(w2, c3.z, a3); a3 = fmaf(w3, c3.w, a3);
        }
        x2[0][t] = pfv[0] + a0; x2[1][t] = pfv[1] + a1;
        x2[2][t] = pfv[2] + a2; x2[3][t] = pfv[3] + a3;
    }
    __syncthreads();
    #pragma unroll
    for (int rep = 0; rep < 2; ++rep) {
        int ch = rep * 256 + t;
        int g = ch >> 6;
        float aq[4] = {0.f, 0.f, 0.f, 0.f};
        #pragma unroll
        for (int ci = 0; ci < 32; ++ci) {
            float w = qwT[ci * INNER + ch];
            aq[0] = fmaf(w, x2[0][g * 32 + ci], aq[0]);
            aq[1] = fmaf(w, x2[1][g * 32 + ci], aq[1]);
            aq[2] = fmaf(w, x2[2][g * 32 + ci], aq[2]);
            aq[3] = fmaf(w, x2[3][g * 32 + ci], aq[3]);
        }
        #pragma unroll
        for (int r = 0; r < 4; ++r) {
            qls[r][ch] = aq[r];
            qT[(b * NQ + n0 + r) * INNER + ch] = aq[r];
        }
    }
    __syncthreads();
    {
        int pr = t >> 3, l = t & 7;
        int r = pr >> 3, g = pr & 7;
        float s0 = 0.f, s1 = 0.f;
        #pragma unroll
        for (int e = 0; e < 8; ++e) {
            int jj = l * 8 + e;
            float ev = gelu_exact(fmaf(qls[r][g * 64 + jj], off_w1[jj], off_b1[jj]));
            s0 = fmaf(ev, off_w2[jj], s0);
            s1 = fmaf(ev, off_w2[64 + jj], s1);
        }
        #pragma unroll
        for (int o = 4; o > 0; o >>= 1) {
            s0 += __shfl_xor(s0, o, 64);
            s1 += __shfl_xor(s1, o, 64);
        }
        if (l == 0) {
            float vgx = g01[r][0] + tanhf(s0) * (2.f / 3.f);
            float vgy = g01[r][1] + tanhf(s1) * (2.f / 3.f);
            vg[r][g][0] = vgx; vg[r][g][1] = vgy;
            float* vp = vgrid_g + ((b * GROUPS + g) * NQ + n0 + r) * 2;
            vp[0] = vgx; vp[1] = vgy;
        }
    }
    __syncthreads();
    #pragma unroll
    for (int rep = 0; rep < 4; ++rep) {
        int idx = rep * 256 + t;
        int r = idx >> 8, c = idx & 255, g = c >> 5;
        float x = (vg[r][g][0] + 1.f) * 2.f - 0.5f;
        float y = (vg[r][g][1] + 1.f) * 2.f - 0.5f;
        float x0f = floorf(x), y0f = floorf(y);
        float wx = x - x0f, wy = y - y0f;
        int x0 = (int)x0f, y0 = (int)y0f;
        const float* img = rgb + (b * DIMC + c) * HWT;
        float v00 = samp4(img, y0, x0), v01 = samp4(img, y0, x0 + 1);
        float v10 = samp4(img, y0 + 1, x0), v11 = samp4(img, y0 + 1, x0 + 1);
        kvs[r][c] = v00 * (1.f - wx) * (1.f - wy) + v01 * wx * (1.f - wy)
                  + v10 * (1.f - wx) * wy + v11 * wx * wy;
    }
    __syncthreads();
    // grouped k/v convs; K transposed [bg][d][n], V row-major [b][n][inner]
    #pragma unroll
    for (int rep = 0; rep < 2; ++rep) {
        int ch = rep * 256 + t;
        int g = ch >> 6;
        float ak[4] = {0.f, 0.f, 0.f, 0.f};
        float av[4] = {0.f, 0.f, 0.f, 0.f};
        #pragma unroll
        for (int ci = 0; ci < 32; ++ci) {
            float wk = kwT[ci * INNER + ch];
            float wv = vwT[ci * INNER + ch];
            #pragma unroll
            for (int r = 0; r < 4; ++r) {
                float x = kvs[r][g * 32 + ci];
                ak[r] = fmaf(wk, x, ak[r]);
                av[r] = fmaf(wv, x, av[r]);
            }
        }
        int hh = ch >> 6, dh = ch & 63;
        float4 kk; kk.x = ak[0]; kk.y = ak[1]; kk.z = ak[2]; kk.w = ak[3];
        *(float4*)(kTt + ((b * HEADS + hh) * DH + dh) * NQ + n0) = kk;
        #pragma unroll
        for (int r = 0; r < 4; ++r)
            vT[(b * NQ + n0 + r) * INNER + ch] = av[r];
    }
}

// ---------------- K3a: CPB bias via MFMA, low-register version ----------------
// grid 4096: blockIdx = ((bg*16 + jt)*8 + itc); wave: 4 j, 2 i-tiles of 16.
// mfma(A=w1, B=h0): C col (lane&15) = output pair (i), C row (4*lgp+reg) = c2.
// w0/b0 held as packed bf16 (24 regs); b1/w2 + vgrid tile in LDS; jj unroll 1.
__global__ __launch_bounds__(256) void k3a_bias(
        const float* __restrict__ pose_init, const float* __restrict__ vgrid_g,
        const float* __restrict__ w0, const float* __restrict__ b0,
        const float* __restrict__ b1, const float* __restrict__ w1,
        const float* __restrict__ w2, const float* __restrict__ b2,
        ushort_t* __restrict__ bias) {
    int bg = blockIdx.x >> 7;
    int jt = (blockIdx.x >> 3) & 15;
    int itc = blockIdx.x & 7;
    int b = bg >> 3;
    int tid = threadIdx.x;
    int wv = tid >> 6, lane = tid & 63;
    int lgp = lane >> 4, lr = lane & 15;

    __shared__ float gx_s[32], gy_s[32];
    __shared__ float2 b1w2_s[64];
    __shared__ float2 vg_s[16];
    if (tid < 32) {
        int i = itc * 32 + tid;
        gx_s[tid] = 2.f * pose_init[(b * 2 + 0) * NQ + i] - 1.f;
        gy_s[tid] = 2.f * pose_init[(b * 2 + 1) * NQ + i] - 1.f;
    } else if (tid >= 64 && tid < 128) {
        int c2 = tid - 64;
        float2 bw; bw.x = b1[c2]; bw.y = w2[c2];
        b1w2_s[c2] = bw;
    } else if (tid >= 128 && tid < 144) {
        int j = jt * 16 + (tid - 128);
        vg_s[tid - 128] = ((const float2*)vgrid_g)[bg * NQ + j];
    }
    __syncthreads();

    // layer-0 weights packed bf16: k = kc*32 + lgp*8 + e, pairs over e
    unsigned w0a_pk[2][4], w0b_pk[2][4], b0_pk[2][4];
    #pragma unroll
    for (int kc = 0; kc < 2; ++kc)
        #pragma unroll
        for (int e2 = 0; e2 < 4; ++e2) {
            int c = kc * 32 + lgp * 8 + 2 * e2;
            w0a_pk[kc][e2] = pack2bf(w0[2 * c], w0[2 * (c + 1)]);
            w0b_pk[kc][e2] = pack2bf(w0[2 * c + 1], w0[2 * (c + 1) + 1]);
            b0_pk[kc][e2]  = pack2bf(b0[c], b0[c + 1]);
        }
    // w1 as A-fragment: row c2 = nt*16 + lr, k = kc*32 + lgp*8 + e
    short8v bw1[2][4];
    #pragma unroll
    for (int nt = 0; nt < 4; ++nt) {
        int c2 = nt * 16 + lr;
        #pragma unroll
        for (int kc = 0; kc < 2; ++kc)
            #pragma unroll
            for (int e = 0; e < 8; ++e)
                bw1[kc][nt][e] = f2bf(w1[c2 * 64 + kc * 32 + lgp * 8 + e]);
    }
    float b2v = b2[0];
    ushort_t* brow_base = bias + bg * NQ * NQ;

    #pragma unroll 1
    for (int it2 = 0; it2 < 2; ++it2) {
        int it = itc * 2 + it2;
        float gxi = gx_s[it2 * 16 + lr], gyi = gy_s[it2 * 16 + lr];
        #pragma unroll 1
        for (int jj = 0; jj < 4; ++jj) {
            int jl = wv * 4 + jj;
            int j = jt * 16 + jl;
            float2 vgv = vg_s[jl];
            float px = gxi - vgv.x, py = gyi - vgv.y;
            float u = copysignf(__logf(1.f + fabsf(px)), px);
            float vvl = copysignf(__logf(1.f + fabsf(py)), py);
            // B-fragment: h0 for col = lr (pair i), k-slices per lgp
            short8v hb0, hb1;
            #pragma unroll
            for (int e2 = 0; e2 < 4; ++e2) {
                float h0a = fmaf(bf2f(w0a_pk[0][e2] & 0xffffu), u,
                            fmaf(bf2f(w0b_pk[0][e2] & 0xffffu), vvl,
                                 bf2f(b0_pk[0][e2] & 0xffffu)));
                float h0b = fmaf(bf2f(w0a_pk[0][e2] >> 16), u,
                            fmaf(bf2f(w0b_pk[0][e2] >> 16), vvl,
                                 bf2f(b0_pk[0][e2] >> 16)));
                hb0[2 * e2]     = f2bf_hw(fmaxf(h0a, 0.f));
                hb0[2 * e2 + 1] = f2bf_hw(fmaxf(h0b, 0.f));
                float h1a = fmaf(bf2f(w0a_pk[1][e2] & 0xffffu), u,
                            fmaf(bf2f(w0b_pk[1][e2] & 0xffffu), vvl,
                                 bf2f(b0_pk[1][e2] & 0xffffu)));
                float h1b = fmaf(bf2f(w0a_pk[1][e2] >> 16), u,
                            fmaf(bf2f(w0b_pk[1][e2] >> 16), vvl,
                                 bf2f(b0_pk[1][e2] >> 16)));
                hb1[2 * e2]     = f2bf_hw(fmaxf(h1a, 0.f));
                hb1[2 * e2 + 1] = f2bf_hw(fmaxf(h1b, 0.f));
            }
            f32x4 acc0 = {0.f, 0.f, 0.f, 0.f};
            f32x4 acc1 = {0.f, 0.f, 0.f, 0.f};
            f32x4 acc2 = {0.f, 0.f, 0.f, 0.f};
            f32x4 acc3 = {0.f, 0.f, 0.f, 0.f};
            acc0 = __builtin_amdgcn_mfma_f32_16x16x32_bf16(bw1[0][0], hb0, acc0, 0, 0, 0);
            acc0 = __builtin_amdgcn_mfma_f32_16x16x32_bf16(bw1[1][0], hb1, acc0, 0, 0, 0);
            acc1 = __builtin_amdgcn_mfma_f32_16x16x32_bf16(bw1[0][1], hb0, acc1, 0, 0, 0);
            acc1 = __builtin_amdgcn_mfma_f32_16x16x32_bf16(bw1[1][1], hb1, acc1, 0, 0, 0);
            acc2 = __builtin_amdgcn_mfma_f32_16x16x32_bf16(bw1[0][2], hb0, acc2, 0, 0, 0);
            acc2 = __builtin_amdgcn_mfma_f32_16x16x32_bf16(bw1[1][2], hb1, acc2, 0, 0, 0);
            acc3 = __builtin_amdgcn_mfma_f32_16x16x32_bf16(bw1[0][3], hb0, acc3, 0, 0, 0);
            acc3 = __builtin_amdgcn_mfma_f32_16x16x32_bf16(bw1[1][3], hb1, acc3, 0, 0, 0);
            // layer-2: c2 = nt*16 + 4*lgp + r; b1/w2 from LDS (broadcast over lr)
            float s = 0.f;
            #pragma unroll
            for (int r = 0; r < 4; ++r) {
                float2 bw00 = b1w2_s[0 * 16 + 4 * lgp + r];
                float2 bw01 = b1w2_s[1 * 16 + 4 * lgp + r];
                float2 bw02 = b1w2_s[2 * 16 + 4 * lgp + r];
                float2 bw03 = b1w2_s[3 * 16 + 4 * lgp + r];
                s += fmaxf(acc0[r] + bw00.x, 0.f) * bw00.y;
                s += fmaxf(acc1[r] + bw01.x, 0.f) * bw01.y;
                s += fmaxf(acc2[r] + bw02.x, 0.f) * bw02.y;
                s += fmaxf(acc3[r] + bw03.x, 0.f) * bw03.y;
            }
            s += __shfl_xor(s, 16, 64);
            s += __shfl_xor(s, 32, 64);
            if (lane < 16)
                brow_base[(it * 16 + lr) * NQ + j] = (ushort_t)f2bf(s + b2v);
        }
    }
}

// ---------------- K3b: sim + bias + softmax + attn@V ----------------
__global__ __launch_bounds__(256) void k3b_attn(
        const float* __restrict__ qT, const float* __restrict__ kTt,
        const float* __restrict__ vT, const ushort_t* __restrict__ bias,
        float* __restrict__ aoT) {
    int bg = blockIdx.x >> 5;
    int itile = blockIdx.x & 31;
    int b = bg >> 3, h = bg & 7;
    int i0 = itile * 8;
    int tid = threadIdx.x;

    __shared__ __align__(16) float q_s[8][64];
    __shared__ __align__(16) float attn_s[8][NQ];
    __shared__ float ssum_s[8];

    for (int idx = tid; idx < 8 * 64; idx += 256) {
        int i = idx >> 6, d = idx & 63;
        q_s[i][d] = qT[(b * NQ + i0 + i) * INNER + h * 64 + d] * 0.125f;
    }
    __syncthreads();

    {
        int jq = tid & 63, ih = tid >> 6;
        const float4* kb4 = (const float4*)(kTt + bg * DH * NQ) + jq;
        float4 s0 = {0.f, 0.f, 0.f, 0.f};
        float4 s1 = {0.f, 0.f, 0.f, 0.f};
        #pragma unroll 4
        for (int d = 0; d < 64; ++d) {
            float4 kv = kb4[d * 64];
            float q0 = q_s[ih][d], q1 = q_s[ih + 4][d];
            s0.x = fmaf(q0, kv.x, s0.x); s0.y = fmaf(q0, kv.y, s0.y);
            s0.z = fmaf(q0, kv.z, s0.z); s0.w = fmaf(q0, kv.w, s0.w);
            s1.x = fmaf(q1, kv.x, s1.x); s1.y = fmaf(q1, kv.y, s1.y);
            s1.z = fmaf(q1, kv.z, s1.z); s1.w = fmaf(q1, kv.w, s1.w);
        }
        uint2 bb0 = *(const uint2*)(bias + (bg * NQ + i0 + ih) * NQ + jq * 4);
        uint2 bb1 = *(const uint2*)(bias + (bg * NQ + i0 + ih + 4) * NQ + jq * 4);
        s0.x += bf2f(bb0.x & 0xffffu); s0.y += bf2f(bb0.x >> 16);
        s0.z += bf2f(bb0.y & 0xffffu); s0.w += bf2f(bb0.y >> 16);
        s1.x += bf2f(bb1.x & 0xffffu); s1.y += bf2f(bb1.x >> 16);
        s1.z += bf2f(bb1.y & 0xffffu); s1.w += bf2f(bb1.y >> 16);
        *(float4*)&attn_s[ih][jq * 4] = s0;
        *(float4*)&attn_s[ih + 4][jq * 4] = s1;
    }
    __syncthreads();
    {
        int il = tid >> 5, lane = tid & 31;
        float m = -1e30f;
        for (int jj = 0; jj < 8; ++jj) m = fmaxf(m, attn_s[il][jj * 32 + lane]);
        #pragma unroll
        for (int o = 16; o > 0; o >>= 1) m = fmaxf(m, __shfl_xor(m, o, 32));
        float s = 0.f;
        for (int jj = 0; jj < 8; ++jj) {
            int j = jj * 32 + lane;
            float e = __expf(attn_s[il][j] - m);
            attn_s[il][j] = e;
            s += e;
        }
        #pragma unroll
        for (int o = 16; o > 0; o >>= 1) s += __shfl_xor(s, o, 32);
        if (lane == 0) ssum_s[il] = s;
    }
    __syncthreads();
    {
        int lane = tid & 31, il = tid >> 5;
        const float2* vp = (const float2*)(vT + b * NQ * INNER + h * 64) + lane;
        float a0 = 0.f, a1 = 0.f, c0 = 0.f, c1 = 0.f;
        #pragma unroll 4
        for (int j = 0; j < NQ; j += 2) {
            float w0 = attn_s[il][j], w1 = attn_s[il][j + 1];
            float2 v0 = vp[j * (INNER / 2)];
            float2 v1 = vp[(j + 1) * (INNER / 2)];
            a0 = fmaf(w0, v0.x, a0); a1 = fmaf(w0, v0.y, a1);
            c0 = fmaf(w1, v1.x, c0); c1 = fmaf(w1, v1.y, c1);
        }
        float r = 1.f / ssum_s[il];
        float2 res; res.x = (a0 + c0) * r; res.y = (a1 + c1) * r;
        *(float2*)(aoT + (b * NQ + i0 + il) * INNER + h * 64 + lane * 2) = res;
    }
}

// ---------------- K4: final projection 512 -> 256 (coalesced owT) ----------------
__global__ __launch_bounds__(256) void k4_proj(const float* __restrict__ aoT,
        const float* __restrict__ owT, const float* __restrict__ out_b,
        float* __restrict__ out) {
    int b = blockIdx.x >> 6;
    int n0 = (blockIdx.x & 63) * 4;
    int t = threadIdx.x;
    __shared__ __align__(16) float xl[4][INNER];
    for (int idx = t; idx < 4 * INNER; idx += 256) {
        xl[idx >> 9][idx & 511] = aoT[(b * NQ + n0) * INNER + idx];
    }
    __syncthreads();
    float bo = out_b[t];
    float a0 = bo, a1 = bo, a2 = bo, a3 = bo;
    #pragma unroll 2
    for (int c4 = 0; c4 < 128; ++c4) {
        int c = c4 * 4;
        float w0 = owT[(c + 0) * DIMC + t];
        float w1 = owT[(c + 1) * DIMC + t];
        float w2 = owT[(c + 2) * DIMC + t];
        float w3 = owT[(c + 3) * DIMC + t];
        float4 x0 = *(const float4*)&xl[0][c];
        float4 x1 = *(const float4*)&xl[1][c];
        float4 x2 = *(const float4*)&xl[2][c];
        float4 x3 = *(const float4*)&xl[3][c];
        a0 = fmaf(w0, x0.x, a0); a0 = fmaf(w1, x0.y, a0); a0 = fmaf(w2, x0.z, a0); a0 = fmaf(w3, x0.w, a0);
        a1 = fmaf(w0, x1.x, a1); a1 = fmaf(w1, x1.y, a1); a1 = fmaf(w2, x1.z, a1); a1 = fmaf(w3, x1.w, a1);
        a2 = fmaf(w0, x2.x, a2); a2 = fmaf(w1, x2.y, a2); a2 = fmaf(w2, x2.z, a2); a2 = fmaf(w3, x2.w, a2);
        a3 = fmaf(w0, x3.x, a3); a3 = fmaf(w1, x3.y, a3); a3 = fmaf(w2, x3.z, a3); a3 = fmaf(w3, x3.w, a3);
    }
    float4 res; res.x = a0; res.y = a1; res.z = a2; res.w = a3;
    *(float4*)(out + (b * DIMC + t) * NQ + n0) = res;
}

extern "C" void kernel_launch(void* const* d_in, const int* in_sizes, int n_in,
                              void* d_out, int out_size, void* d_ws, size_t ws_size,
                              hipStream_t stream) {
    const float* pose_feat = (const float*)d_in[0];
    const float* rgb       = (const float*)d_in[1];
    const float* pose_init = (const float*)d_in[2];
    const float* mha_in_w  = (const float*)d_in[3];
    const float* mha_in_b  = (const float*)d_in[4];
    const float* mha_out_w = (const float*)d_in[5];
    const float* mha_out_b = (const float*)d_in[6];
    const float* pe_gauss  = (const float*)d_in[7];
    const float* off_w1    = (const float*)d_in[8];
    const float* off_b1    = (const float*)d_in[9];
    const float* off_w2    = (const float*)d_in[10];
    const float* cpb_w0    = (const float*)d_in[11];
    const float* cpb_b0    = (const float*)d_in[12];
    const float* cpb_w1    = (const float*)d_in[13];
    const float* cpb_b1    = (const float*)d_in[14];
    const float* cpb_w2    = (const float*)d_in[15];
    const float* cpb_b2    = (const float*)d_in[16];
    const float* q_w       = (const float*)d_in[17];
    const float* k_w       = (const float*)d_in[18];
    const float* v_w       = (const float*)d_in[19];
    const float* out_w     = (const float*)d_in[20];
    const float* out_b     = (const float*)d_in[21];

    float* ws    = (float*)d_ws;
    float* kx    = ws;                     // 16384
    float* vx    = kx + 16384;             // 16384
    float* qT    = vx + 16384;             // 524288
    float* kTt   = qT + 524288;            // 524288
    float* vT    = kTt + 524288;           // 524288
    float* vgrid = vT + 524288;            // 16384
    float* aoT   = vgrid + 16384;          // 524288
    float* WqT   = aoT + 524288;           // 65536
    float* mowT  = WqT + 65536;            // 65536
    float* owT   = mowT + 65536;           // 131072
    float* qwT   = owT + 131072;           // 16384
    float* kwT   = qwT + 16384;            // 16384
    float* vwT   = kwT + 16384;            // 16384
    ushort_t* bias = (ushort_t*)(vwT + 16384);   // 32*256*256 bf16 = 4 MB
    float* out   = (float*)d_out;

    k0_tr<<<1216, 256, 0, stream>>>(mha_in_w, mha_out_w, out_w, q_w, k_w, v_w,
        WqT, mowT, owT, qwT, kwT, vwT);
    k1_kv<<<64, 256, 0, stream>>>(rgb, mha_in_w, mha_in_b, kx, vx);
    k2_qkv<<<256, 256, 0, stream>>>(pose_feat, rgb, pose_init, mha_in_b,
        WqT, mowT, mha_out_b, pe_gauss, off_w1, off_b1, off_w2, qwT, kwT, vwT,
        kx, vx, qT, kTt, vT, vgrid);
    k3a_bias<<<4096, 256, 0, stream>>>(pose_init, vgrid,
        cpb_w0, cpb_b0, cpb_b1, cpb_w1, cpb_w2, cpb_b2, bias);
    k3b_attn<<<1024, 256, 0, stream>>>(qT, kTt, vT, bias, aoT);
    k4_proj<<<256, 256, 0, stream>>>(aoT, owT, out_b, out);
}